// Round 2
// baseline (1279.213 us; speedup 1.0000x reference)
//
#include <hip/hip_runtime.h>
#include <hip/hip_bf16.h>
#include <math.h>

// ---------------------------------------------------------------------------
// helpers
// ---------------------------------------------------------------------------
typedef __bf16 v8bf __attribute__((ext_vector_type(8)));
typedef float  v4f  __attribute__((ext_vector_type(4)));
typedef unsigned short v8us __attribute__((ext_vector_type(8)));

__device__ __forceinline__ unsigned short f2bfu(float f) {
    unsigned u = __builtin_bit_cast(unsigned, f);
    unsigned r = (u + 0x7fffu + ((u >> 16) & 1u)) >> 16;
    return (unsigned short)r;
}
__device__ __forceinline__ float bf2f(unsigned short u) {
    unsigned x = ((unsigned)u) << 16;
    return __builtin_bit_cast(float, x);
}

// fragment-swizzled element address: matrix [rows][K cols] stored so that a
// wave's 16x32 MFMA fragment is contiguous: sw(r,k) =
//   tile(r>>4, k>>5) * 512 + lane((k>>3)&3, r&15) * 8 + (k&7)
__device__ __forceinline__ long long swidx(int r, int k, int kt /*=K>>5*/) {
    return ((long long)((r >> 4) * kt + (k >> 5)) << 9)
         + (((k >> 3) & 3) << 7) + ((r & 15) << 3) + (k & 7);
}

#define GLDS16(g, s)                                                        \
    __builtin_amdgcn_global_load_lds(                                       \
        (const __attribute__((address_space(1))) void*)(g),                 \
        (__attribute__((address_space(3))) void*)(s), 16, 0, 0)

// ---------------------------------------------------------------------------
// SWIZZLED bf16 MFMA GEMM, 128x128 tile, LDS-staged (m97 structure).
// A (M x K) and B (N x K) are in fragment-swizzled layout (see swidx), so
// each 16x32 fragment is a contiguous 1KB block with lane l owning bytes
// [16l,16l+16) — exactly global_load_lds's wave-uniform-dest + lane*16
// write pattern. Per BK=32 chunk: the 4 waves stage 16 fragments (8 A row-
// tiles + 8 B col-tiles, 4 GLDS/wave) into a double-buffered LDS; each wave
// ds_reads its 4 A + 4 B fragments (conflict-free contiguous 1KB reads) and
// issues 16 MFMAs into a 64x64 accumulator. R1 established the register-
// direct version is BW-bound through L1 (22.3 TB/s delivered = 487 TF);
// LDS staging removes the 2x intra-block redundancy and moves the register
// fill onto the 128B/cy LDS path.
// Outputs: Cf (fp32,+res row-major) | Cb (bf16 row-major) | Csw (bf16
// swizzled for the next GEMM, K_consumer = N) ; cols >= ctcol0 (Ct!=null)
// go transposed to Ct (attention V^T). M,N multiples of 128, K of 32.
// ---------------------------------------------------------------------------
__global__ __launch_bounds__(256) void gemm_sw_k(
    const unsigned short* __restrict__ Asw,
    const unsigned short* __restrict__ Bsw,
    const float* __restrict__ bias,
    const float* __restrict__ res,
    float* __restrict__ Cf,
    unsigned short* __restrict__ Cb,
    unsigned short* __restrict__ Csw,
    unsigned short* __restrict__ Ct, int ctcol0,
    int M, int N, int K, int ldC, int relu)
{
    __shared__ __align__(16) unsigned short As[2][8][512];
    __shared__ __align__(16) unsigned short Bs[2][8][512];
    const int t = threadIdx.x;
    const int w = t >> 6;
    const int l = t & 63;

    int bx = blockIdx.x, by = blockIdx.y;
    {
        int nbx = gridDim.x;
        int nb  = nbx * gridDim.y;
        if ((nb & 7) == 0) {
            int bid = by * nbx + bx;
            int nid = (bid & 7) * (nb >> 3) + (bid >> 3);
            by = nid / nbx;
            bx = nid - by * nbx;
        }
    }
    const int m0 = by * 128;
    const int n0 = bx * 128;
    const int r16 = l & 15;
    const int qb  = l >> 4;
    const int wm = w >> 1, wn = w & 1;
    const int kt = K >> 5;

    // staging sources: wave w stages A row-tiles {2w,2w+1}, B col-tiles {2w,2w+1}
    const unsigned short* gA0 = Asw + (((long long)((m0 >> 4) + 2 * w) * kt) << 9) + l * 8;
    const unsigned short* gA1 = gA0 + ((long long)kt << 9);
    const unsigned short* gB0 = Bsw + (((long long)((n0 >> 4) + 2 * w) * kt) << 9) + l * 8;
    const unsigned short* gB1 = gB0 + ((long long)kt << 9);

    v4f acc[4][4];
#pragma unroll
    for (int i = 0; i < 4; i++)
#pragma unroll
        for (int j = 0; j < 4; j++) acc[i][j] = (v4f){0.f, 0.f, 0.f, 0.f};

    // prologue: stage chunk 0 into buffer 0
    GLDS16(gA0, &As[0][2 * w + 0][0]);
    GLDS16(gA1, &As[0][2 * w + 1][0]);
    GLDS16(gB0, &Bs[0][2 * w + 0][0]);
    GLDS16(gB1, &Bs[0][2 * w + 1][0]);
    __syncthreads();

    int cur = 0;
    for (int c = 1; c < kt; c++) {
        const long long o = (long long)c << 9;
        // stage next chunk first (loads stay in flight under ds_read+MFMA)
        GLDS16(gA0 + o, &As[cur ^ 1][2 * w + 0][0]);
        GLDS16(gA1 + o, &As[cur ^ 1][2 * w + 1][0]);
        GLDS16(gB0 + o, &Bs[cur ^ 1][2 * w + 0][0]);
        GLDS16(gB1 + o, &Bs[cur ^ 1][2 * w + 1][0]);
        v8bf af[4], bfr[4];
#pragma unroll
        for (int i = 0; i < 4; i++) af[i]  = *(const v8bf*)(&As[cur][4 * wm + i][l * 8]);
#pragma unroll
        for (int j = 0; j < 4; j++) bfr[j] = *(const v8bf*)(&Bs[cur][4 * wn + j][l * 8]);
#pragma unroll
        for (int i = 0; i < 4; i++)
#pragma unroll
            for (int j = 0; j < 4; j++)
                acc[i][j] = __builtin_amdgcn_mfma_f32_16x16x32_bf16(
                    af[i], bfr[j], acc[i][j], 0, 0, 0);
        __syncthreads();
        cur ^= 1;
    }
    {
        v8bf af[4], bfr[4];
#pragma unroll
        for (int i = 0; i < 4; i++) af[i]  = *(const v8bf*)(&As[cur][4 * wm + i][l * 8]);
#pragma unroll
        for (int j = 0; j < 4; j++) bfr[j] = *(const v8bf*)(&Bs[cur][4 * wn + j][l * 8]);
#pragma unroll
        for (int i = 0; i < 4; i++)
#pragma unroll
            for (int j = 0; j < 4; j++)
                acc[i][j] = __builtin_amdgcn_mfma_f32_16x16x32_bf16(
                    af[i], bfr[j], acc[i][j], 0, 0, 0);
    }

    float bv[4];
#pragma unroll
    for (int j = 0; j < 4; j++) bv[j] = bias[n0 + 64 * wn + 16 * j + r16];
    const int colbase = n0 + 64 * wn + r16;
    const int nt = N >> 5;
#pragma unroll
    for (int i = 0; i < 4; i++) {
        int rowb = m0 + 64 * wm + 16 * i + qb * 4;
#pragma unroll
        for (int j = 0; j < 4; j++) {
            int col = colbase + 16 * j;
            float v[4];
#pragma unroll
            for (int r = 0; r < 4; r++) v[r] = acc[i][j][r] + bv[j];
            if (Ct && col >= ctcol0) {
                ushort4 o;
                o.x = f2bfu(v[0]); o.y = f2bfu(v[1]);
                o.z = f2bfu(v[2]); o.w = f2bfu(v[3]);
                *(ushort4*)(Ct + ((long long)(rowb >> 10) << 20)
                            + (long long)(col - ctcol0) * 1024 + (rowb & 1023)) = o;
            } else if (Csw) {
#pragma unroll
                for (int r = 0; r < 4; r++) {
                    int row = rowb + r;
                    float vv = v[r];
                    if (relu) vv = fmaxf(vv, 0.f);
                    Csw[swidx(row, col, nt)] = f2bfu(vv);
                }
            } else {
#pragma unroll
                for (int r = 0; r < 4; r++) {
                    int row = rowb + r;
                    long long off = (long long)row * ldC + col;
                    float vv = v[r];
                    if (res)  vv += res[off];
                    if (relu) vv = fmaxf(vv, 0.f);
                    if (Cf) Cf[off] = vv;
                    if (Cb) ((unsigned short*)Cb)[off] = f2bfu(vv);
                }
            }
        }
    }
}

// ---------------------------------------------------------------------------
// LDS-staged GEMM (R5) — kept for the conv frontend (row-remapped A).
// ---------------------------------------------------------------------------
__global__ __launch_bounds__(256) void gemm_mfma_k(
    const __hip_bfloat16* __restrict__ A, int rpbA, long long bstrideA, int ldA,
    const __hip_bfloat16* __restrict__ B,
    const float* __restrict__ bias,
    const float* __restrict__ res,
    float* __restrict__ Cf,
    __hip_bfloat16* __restrict__ Cb,
    int M, int N, int K, int ldC, int relu)
{
    __shared__ __align__(16) __hip_bfloat16 As[2][8][64][8];
    __shared__ __align__(16) __hip_bfloat16 Bs[2][4][64][8];
    const int t  = threadIdx.x;
    const int w  = t >> 6;
    const int l  = t & 63;
    const int m0 = blockIdx.y * 128;
    const int n0 = blockIdx.x * 64;
    const int r16 = l & 15;
    const int qb  = l >> 4;
    const int wm = w >> 1, wn = w & 1;

    const __hip_bfloat16* gA[2];
#pragma unroll
    for (int tt = 0; tt < 2; tt++) {
        int arow = m0 + 16 * (2 * w + tt) + r16;
        gA[tt] = A + (long long)(arow / rpbA) * bstrideA
                   + (long long)(arow % rpbA) * ldA + qb * 8;
    }
    const __hip_bfloat16* gB = B + (long long)(n0 + 16 * w + r16) * K + qb * 8;

    v4f acc[4][2];
#pragma unroll
    for (int i = 0; i < 4; i++)
#pragma unroll
        for (int j = 0; j < 2; j++) acc[i][j] = (v4f){0.f, 0.f, 0.f, 0.f};

    GLDS16(gA[0], &As[0][2 * w + 0][0][0]);
    GLDS16(gA[1], &As[0][2 * w + 1][0][0]);
    GLDS16(gB,    &Bs[0][w][0][0]);
    __syncthreads();

    int cur = 0;
    for (int k0 = 32; k0 < K; k0 += 32) {
        v8bf af[4], bfr[2];
#pragma unroll
        for (int i = 0; i < 4; i++) af[i]  = *(const v8bf*)(&As[cur][4 * wm + i][l][0]);
#pragma unroll
        for (int j = 0; j < 2; j++) bfr[j] = *(const v8bf*)(&Bs[cur][2 * wn + j][l][0]);
        GLDS16(gA[0] + k0, &As[cur ^ 1][2 * w + 0][0][0]);
        GLDS16(gA[1] + k0, &As[cur ^ 1][2 * w + 1][0][0]);
        GLDS16(gB + k0,    &Bs[cur ^ 1][w][0][0]);
#pragma unroll
        for (int i = 0; i < 4; i++)
#pragma unroll
            for (int j = 0; j < 2; j++)
                acc[i][j] = __builtin_amdgcn_mfma_f32_16x16x32_bf16(
                    af[i], bfr[j], acc[i][j], 0, 0, 0);
        __syncthreads();
        cur ^= 1;
    }
    {
        v8bf af[4], bfr[2];
#pragma unroll
        for (int i = 0; i < 4; i++) af[i]  = *(const v8bf*)(&As[cur][4 * wm + i][l][0]);
#pragma unroll
        for (int j = 0; j < 2; j++) bfr[j] = *(const v8bf*)(&Bs[cur][2 * wn + j][l][0]);
#pragma unroll
        for (int i = 0; i < 4; i++)
#pragma unroll
            for (int j = 0; j < 2; j++)
                acc[i][j] = __builtin_amdgcn_mfma_f32_16x16x32_bf16(
                    af[i], bfr[j], acc[i][j], 0, 0, 0);
    }

    float bv[2];
#pragma unroll
    for (int j = 0; j < 2; j++) bv[j] = bias[n0 + 32 * wn + 16 * j + r16];
    const int colbase = n0 + 32 * wn + r16;
#pragma unroll
    for (int i = 0; i < 4; i++) {
        int rowb = m0 + 64 * wm + 16 * i + qb * 4;
#pragma unroll
        for (int j = 0; j < 2; j++) {
            int col = colbase + 16 * j;
#pragma unroll
            for (int r = 0; r < 4; r++) {
                int row = rowb + r;
                if (row >= M) continue;
                long long off = (long long)row * ldC + col;
                float vv = acc[i][j][r] + bv[j];
                if (res)  vv += res[off];
                if (relu) vv = fmaxf(vv, 0.f);
                if (Cf) Cf[off] = vv;
                if (Cb) ((unsigned short*)Cb)[off] = f2bfu(vv);
            }
        }
    }
}

// ---------------------------------------------------------------------------
// MFMA softsign attention. Output written in SWIZZLED layout (K=1024 -> 32).
// ---------------------------------------------------------------------------
__global__ __launch_bounds__(256) void attn_mfma_k(
    const unsigned short* __restrict__ QKV,
    const unsigned short* __restrict__ Vt,
    unsigned short* __restrict__ Osw)
{
    __shared__ __align__(16) unsigned short lds[25600];
    const int t = threadIdx.x, w = t >> 6, l = t & 63;
    const int bh = blockIdx.y, b = bh >> 4, h = bh & 15;
    const int s0 = blockIdx.x << 7;
    const int r16 = l & 15, q4 = l >> 4;
    const long long qrow0 = (long long)(b << 10) + s0;
    const int hoff = h << 6;

#pragma unroll
    for (int mi = 0; mi < 2; mi++)
#pragma unroll
        for (int kk = 0; kk < 2; kk++) {
            const unsigned short* g = QKV + (qrow0 + 32 * w + 16 * mi + r16) * 3072
                                      + hoff + 32 * kk + q4 * 8;
            GLDS16(g, &lds[(w * 4 + mi * 2 + kk) * 512]);
        }
    __syncthreads();
    v8bf qf[2][2];
#pragma unroll
    for (int mi = 0; mi < 2; mi++)
#pragma unroll
        for (int kk = 0; kk < 2; kk++)
            qf[mi][kk] = *(const v8bf*)&lds[(w * 4 + mi * 2 + kk) * 512 + l * 8];

    v4f oacc[2][4];
#pragma unroll
    for (int i = 0; i < 2; i++)
#pragma unroll
        for (int j = 0; j < 4; j++) oacc[i][j] = (v4f){0.f, 0.f, 0.f, 0.f};

    for (int t0 = 0; t0 < 1024; t0 += 64) {
#pragma unroll
        for (int rr = 0; rr < 2; rr++) {
            int r = 2 * w + rr, kk = r >> 2, j = r & 3;
            const unsigned short* gk = QKV
                + ((long long)(b << 10) + t0 + 16 * j + r16) * 3072
                + 1024 + hoff + 32 * kk + q4 * 8;
            GLDS16(gk, &lds[8192 + r * 512]);
            const unsigned short* gv = Vt + ((long long)b << 20)
                + (long long)(hoff + 16 * j + r16) * 1024 + t0 + 32 * kk + q4 * 8;
            GLDS16(gv, &lds[12288 + r * 512]);
        }
        __syncthreads();

        v8bf kf[2][4];
#pragma unroll
        for (int kk = 0; kk < 2; kk++)
#pragma unroll
            for (int j = 0; j < 4; j++)
                kf[kk][j] = *(const v8bf*)&lds[8192 + (kk * 4 + j) * 512 + l * 8];
        v4f sc[2][4];
#pragma unroll
        for (int i = 0; i < 2; i++)
#pragma unroll
            for (int j = 0; j < 4; j++) sc[i][j] = (v4f){0.f, 0.f, 0.f, 0.f};
#pragma unroll
        for (int kk = 0; kk < 2; kk++)
#pragma unroll
            for (int mi = 0; mi < 2; mi++)
#pragma unroll
                for (int j = 0; j < 4; j++)
                    sc[mi][j] = __builtin_amdgcn_mfma_f32_16x16x32_bf16(
                        qf[mi][kk], kf[kk][j], sc[mi][j], 0, 0, 0);

#pragma unroll
        for (int mi = 0; mi < 2; mi++)
#pragma unroll
            for (int j = 0; j < 4; j++)
#pragma unroll
                for (int r = 0; r < 4; r++) {
                    float v = sc[mi][j][r] * 0.125f;
                    float p = v * __builtin_amdgcn_rcpf(1.0f + fabsf(v));
                    lds[16384 + (32 * w + 16 * mi + q4 * 4 + r) * 72 + 16 * j + r16] = f2bfu(p);
                }

        v8bf pf[2][2], vf[2][4];
#pragma unroll
        for (int mi = 0; mi < 2; mi++)
#pragma unroll
            for (int kk = 0; kk < 2; kk++)
                pf[mi][kk] = *(const v8bf*)&lds[16384 + (32 * w + 16 * mi + r16) * 72
                                                + 32 * kk + q4 * 8];
#pragma unroll
        for (int kk = 0; kk < 2; kk++)
#pragma unroll
            for (int j = 0; j < 4; j++)
                vf[kk][j] = *(const v8bf*)&lds[12288 + (kk * 4 + j) * 512 + l * 8];
#pragma unroll
        for (int kk = 0; kk < 2; kk++)
#pragma unroll
            for (int mi = 0; mi < 2; mi++)
#pragma unroll
                for (int j = 0; j < 4; j++)
                    oacc[mi][j] = __builtin_amdgcn_mfma_f32_16x16x32_bf16(
                        pf[mi][kk], vf[kk][j], oacc[mi][j], 0, 0, 0);
        __syncthreads();
    }

#pragma unroll
    for (int mi = 0; mi < 2; mi++)
#pragma unroll
        for (int j = 0; j < 4; j++)
#pragma unroll
            for (int r = 0; r < 4; r++)
                lds[(32 * w + 16 * mi + q4 * 4 + r) * 72 + 16 * j + r16] =
                    f2bfu(oacc[mi][j][r]);
    __syncthreads();
    {
        int row = t >> 1, ch = (t & 1) << 5;
        int grow = (int)qrow0 + row;
#pragma unroll
        for (int i = 0; i < 4; i++) {
            int c0 = hoff + ch + 8 * i;
            v8us vv = *(const v8us*)&lds[row * 72 + ch + 8 * i];
            *(v8us*)(Osw + swidx(grow, c0, 32)) = vv;
        }
    }
}

// ---------------------------------------------------------------------------
// LayerNorm (torch-style), output bf16 in SWIZZLED layout (K=1024).
// ---------------------------------------------------------------------------
__global__ __launch_bounds__(256) void layernorm_k(
    const float* __restrict__ x, const float* __restrict__ w,
    const float* __restrict__ b, unsigned short* __restrict__ ysw)
{
    int row = blockIdx.x;
    int t = threadIdx.x;
    float4 v = ((const float4*)(x + ((long long)row << 10)))[t];
    float s = v.x + v.y + v.z + v.w;
#pragma unroll
    for (int o = 32; o; o >>= 1) s += __shfl_down(s, o);
    __shared__ float red[4];
    __shared__ float red2[4];
    int wid = t >> 6, lane = t & 63;
    if (lane == 0) red[wid] = s;
    __syncthreads();
    float mean = (red[0] + red[1] + red[2] + red[3]) * (1.0f / 1024.0f);
    float dx = v.x - mean, dy = v.y - mean, dz = v.z - mean, dw = v.w - mean;
    float sq = dx * dx + dy * dy + dz * dz + dw * dw;
#pragma unroll
    for (int o = 32; o; o >>= 1) sq += __shfl_down(sq, o);
    if (lane == 0) red2[wid] = sq;
    __syncthreads();
    float var = (red2[0] + red2[1] + red2[2] + red2[3]) * (1.0f / 1023.0f);
    float inv = 1.0f / (sqrtf(var) + 1e-6f);
    float4 W  = ((const float4*)w)[t];
    float4 Bv = ((const float4*)b)[t];
    ushort4 o;
    o.x = f2bfu(W.x * (dx * inv) + Bv.x);
    o.y = f2bfu(W.y * (dy * inv) + Bv.y);
    o.z = f2bfu(W.z * (dz * inv) + Bv.z);
    o.w = f2bfu(W.w * (dw * inv) + Bv.w);
    int c0 = t << 2;
    *(ushort4*)(ysw + swidx(row, c0, 32)) = o;
}

// ---------------------------------------------------------------------------
__global__ __launch_bounds__(256) void add_pos_k(float* __restrict__ h)
{
    int idx = blockIdx.x * 256 + threadIdx.x;
    int d = idx & 1023;
    int s = (idx >> 10) & 1023;
    int e = d & ~1;
    float div = expf(-9.210340371976184f * (float)e * (1.0f / 1024.0f));
    float arg = (float)s * div;
    float pe = (d & 1) ? cosf(arg) : sinf(arg);
    h[idx] += pe;
}

__global__ __launch_bounds__(256) void convert_k(
    const float* __restrict__ src, unsigned short* __restrict__ dst, int n4)
{
    int i = blockIdx.x * 256 + threadIdx.x;
    if (i >= n4) return;
    float4 v = ((const float4*)src)[i];
    ushort4 o;
    o.x = f2bfu(v.x); o.y = f2bfu(v.y); o.z = f2bfu(v.z); o.w = f2bfu(v.w);
    ((ushort4*)dst)[i] = o;
}

// Layer weights fp32 row-major -> bf16 SWIZZLED, all 6 matrices, one launch.
// dst layout (us): q,k,v,o (1M each), f1 (2M), f2 (2M) — contiguous.
__global__ __launch_bounds__(256) void convert_layer_sw_k(
    const float* __restrict__ q, const float* __restrict__ k,
    const float* __restrict__ v, const float* __restrict__ o,
    const float* __restrict__ f1, const float* __restrict__ f2,
    unsigned short* __restrict__ dst)
{
    int idx = blockIdx.x * 256 + threadIdx.x;   // float4 index, [0, 2M)
    const float* src;
    unsigned short* db;
    int Ksh, rf;
    if (idx < 0x100000) {
        int region = idx >> 18;
        rf = idx & 0x3FFFF;
        src = (region == 0) ? q : (region == 1) ? k : (region == 2) ? v : o;
        db = dst + ((long long)region << 20);
        Ksh = 10;
    } else if (idx < 0x180000) {
        rf = idx - 0x100000; src = f1; db = dst + (4LL << 20); Ksh = 10;
    } else {
        rf = idx - 0x180000; src = f2; db = dst + (6LL << 20); Ksh = 11;
    }
    float4 vv = ((const float4*)src)[rf];
    int flatf = rf << 2;
    int n  = flatf >> Ksh;
    int k0 = flatf & ((1 << Ksh) - 1);
    ushort4 ov;
    ov.x = f2bfu(vv.x); ov.y = f2bfu(vv.y); ov.z = f2bfu(vv.z); ov.w = f2bfu(vv.w);
    *(ushort4*)(db + swidx(n, k0, 1 << (Ksh - 5))) = ov;
}

__global__ __launch_bounds__(256) void concat3_k(
    const float* __restrict__ a, const float* __restrict__ b,
    const float* __restrict__ c, float* __restrict__ o)
{
    int i = blockIdx.x * 256 + threadIdx.x;
    o[i] = (i < 1024) ? a[i] : ((i < 2048) ? b[i - 1024] : c[i - 2048]);
}

__global__ __launch_bounds__(256) void reorder_w_k(
    const float* __restrict__ src, unsigned short* __restrict__ dst, int OC, int IC)
{
    int idx = blockIdx.x * 256 + threadIdx.x;
    if (idx >= OC * IC * 3) return;
    int k  = idx % 3;
    int ic = (idx / 3) % IC;
    int oc = idx / (3 * IC);
    dst[(oc * 3 + k) * IC + ic] = f2bfu(src[idx]);
}

// meanpool split: 256-block partial pass (16 rows each, all 1024 d) then a
// 16-block reduce. Old single-pass version ran on only 16 CUs pulling 16 MB.
__global__ __launch_bounds__(256) void meanpool_part_k(
    const float* __restrict__ h, float* __restrict__ part)
{
    int g = blockIdx.x;                 // g = b*64 + rblk
    int b = g >> 6, rblk = g & 63;
    const float4* base = (const float4*)(h + ((long long)b << 20)
                                           + ((long long)(rblk * 16) << 10));
    float4 s = {0.f, 0.f, 0.f, 0.f};
#pragma unroll
    for (int i = 0; i < 16; i++) {
        float4 v = base[i * 256 + threadIdx.x];
        s.x += v.x; s.y += v.y; s.z += v.z; s.w += v.w;
    }
    ((float4*)part)[g * 256 + threadIdx.x] = s;
}

__global__ __launch_bounds__(256) void meanpool_red_k(
    const float* __restrict__ part, float* __restrict__ pooled)
{
    int idx = blockIdx.x * 256 + threadIdx.x;   // 4096: b = idx>>10, d = idx&1023
    int b = idx >> 10, d = idx & 1023;
    const float* p = part + ((long long)(b * 64) << 10) + d;
    float s = 0.f;
#pragma unroll 8
    for (int r = 0; r < 64; r++) s += p[r << 10];
    pooled[idx] = s * (1.0f / 1024.0f);
}

__global__ __launch_bounds__(256) void fc_k(
    const float* __restrict__ p, const float* __restrict__ w,
    const float* __restrict__ fb, float* __restrict__ out)
{
    int b = blockIdx.x, t = threadIdx.x;
    float s = 0.f;
    for (int i = t; i < 1024; i += 256) s += p[(b << 10) + i] * w[i];
#pragma unroll
    for (int o = 32; o; o >>= 1) s += __shfl_down(s, o);
    __shared__ float red[4];
    if ((t & 63) == 0) red[t >> 6] = s;
    __syncthreads();
    if (t == 0) out[b] = red[0] + red[1] + red[2] + red[3] + fb[0];
}

// ---------------------------------------------------------------------------
extern "C" void kernel_launch(void* const* d_in, const int* in_sizes, int n_in,
                              void* d_out, int out_size, void* d_ws, size_t ws_size,
                              hipStream_t stream)
{
    const float* x    = (const float*)d_in[0];
    const float* c1w  = (const float*)d_in[1];
    const float* c1b  = (const float*)d_in[2];
    const float* c2w  = (const float*)d_in[3];
    const float* c2b  = (const float*)d_in[4];
    const float* lnAw = (const float*)d_in[5];
    const float* lnAb = (const float*)d_in[6];
    const float* qw   = (const float*)d_in[7];
    const float* qbi  = (const float*)d_in[8];
    const float* kw   = (const float*)d_in[9];
    const float* kbi  = (const float*)d_in[10];
    const float* vw   = (const float*)d_in[11];
    const float* vbi  = (const float*)d_in[12];
    const float* ow   = (const float*)d_in[13];
    const float* obi  = (const float*)d_in[14];
    const float* lnBw = (const float*)d_in[15];
    const float* lnBb = (const float*)d_in[16];
    const float* f1w  = (const float*)d_in[17];
    const float* f1b  = (const float*)d_in[18];
    const float* f2w  = (const float*)d_in[19];
    const float* f2b  = (const float*)d_in[20];
    const float* fcw  = (const float*)d_in[21];
    const float* fcb  = (const float*)d_in[22];
    float* out = (float*)d_out;

    float* ws = (float*)d_ws;
    typedef __hip_bfloat16 bf;
    typedef unsigned short us;
    float* h    = ws;                          // 4,194,304 f
    us* hn_b    = (us*)(ws + 4194304);         // 4M us (swizzled activations)
    us* qkv_b   = (us*)(ws + 6291456);         // [4096][3072] us row-major
    us* ff_b    = qkv_b;                       // [4096][2048] swizzled overlay
    us* wq_b    = (us*)(ws + 12582912);        // swizzled: q,k,v,o,f1,f2
    us* wo_b    = (us*)(ws + 14155776);
    us* wf1_b   = (us*)(ws + 14680064);
    us* wf2_b   = (us*)(ws + 15728640);
    us* xb      = (us*)(ws + 16777216);
    us* h1b     = (us*)(ws + 16912896);
    us* w1t_b   = (us*)(ws + 17963520);
    us* w2t_b   = (us*)(ws + 18012672);
    float* pooled = ws + 18799104;             // 4,096 f
    us* Vt      = (us*)(ws + 18803200);        // [4][1024 d][1024 t] us
    float* bqkv = ws + 20900352;               // 3,072 f
    float* mp_part = ws + 20903424;            // 262,144 f (meanpool partials)

    convert_k<<<dim3(257), 256, 0, stream>>>(x, xb, 65792);
    reorder_w_k<<<dim3(384),  256, 0, stream>>>(c1w, w1t_b, 512, 64);
    reorder_w_k<<<dim3(6144), 256, 0, stream>>>(c2w, w2t_b, 1024, 512);

    // conv1: M=4104, N=512, K=192 (LDS-staged kernel, row-remapped A)
    gemm_mfma_k<<<dim3(8, 33), 256, 0, stream>>>(
        (const bf*)xb, 1026, 1028LL * 64, 64, (const bf*)w1t_b,
        c1b, nullptr, nullptr, (bf*)h1b, 4104, 512, 192, 512, 0);
    // conv2: M=4096, N=1024, K=1536
    gemm_mfma_k<<<dim3(16, 32), 256, 0, stream>>>(
        (const bf*)h1b, 1024, 1026LL * 512, 512, (const bf*)w2t_b,
        c2b, nullptr, h, nullptr, 4096, 1024, 1536, 1024, 0);
    add_pos_k<<<dim3(16384), 256, 0, stream>>>(h);

    for (int l = 0; l < 4; l++) {
        long long wo  = (long long)l * 1048576;
        long long wo2 = (long long)l * 2097152;
        convert_layer_sw_k<<<dim3(8192), 256, 0, stream>>>(
            qw + wo, kw + wo, vw + wo, ow + wo, f1w + wo2, f2w + wo2, wq_b);
        concat3_k<<<dim3(12), 256, 0, stream>>>(qbi + l * 1024, kbi + l * 1024,
                                                vbi + l * 1024, bqkv);

        layernorm_k<<<dim3(4096), 256, 0, stream>>>(h, lnAw + l * 1024, lnAb + l * 1024, hn_b);
        // fused QKV: N=3072; Q,K swizzled to qkv_b; V transposed to Vt
        gemm_sw_k<<<dim3(24, 32), 256, 0, stream>>>(
            hn_b, wq_b, bqkv, nullptr, nullptr, qkv_b, nullptr, Vt, 2048,
            4096, 3072, 1024, 3072, 0);
        attn_mfma_k<<<dim3(8, 64), 256, 0, stream>>>(qkv_b, Vt, hn_b);
        // O-proj: out fp32 h += res
        gemm_sw_k<<<dim3(8, 32), 256, 0, stream>>>(
            hn_b, wo_b, obi + l * 1024, h, h, nullptr, nullptr, nullptr, 0,
            4096, 1024, 1024, 1024, 0);
        layernorm_k<<<dim3(4096), 256, 0, stream>>>(h, lnBw + l * 1024, lnBb + l * 1024, hn_b);
        // FF1: out swizzled bf16 (+relu)
        gemm_sw_k<<<dim3(16, 32), 256, 0, stream>>>(
            hn_b, wf1_b, f1b + l * 2048, nullptr, nullptr, nullptr, ff_b, nullptr, 0,
            4096, 2048, 1024, 2048, 1);
        // FF2: out fp32 h += res
        gemm_sw_k<<<dim3(8, 32), 256, 0, stream>>>(
            ff_b, wf2_b, f2b + l * 1024, h, h, nullptr, nullptr, nullptr, 0,
            4096, 1024, 2048, 1024, 0);
    }

    meanpool_part_k<<<dim3(256), 256, 0, stream>>>(h, mp_part);
    meanpool_red_k<<<dim3(16), 256, 0, stream>>>(mp_part, pooled);
    fc_k<<<dim3(4), 256, 0, stream>>>(pooled, fcw, fcb, out);
}

// Round 3
// 1164.410 us; speedup vs baseline: 1.0986x; 1.0986x over previous
//
#include <hip/hip_runtime.h>
#include <hip/hip_bf16.h>
#include <math.h>

// ---------------------------------------------------------------------------
// helpers
// ---------------------------------------------------------------------------
typedef __bf16 v8bf __attribute__((ext_vector_type(8)));
typedef float  v4f  __attribute__((ext_vector_type(4)));
typedef unsigned short v8us __attribute__((ext_vector_type(8)));

__device__ __forceinline__ unsigned short f2bfu(float f) {
    unsigned u = __builtin_bit_cast(unsigned, f);
    unsigned r = (u + 0x7fffu + ((u >> 16) & 1u)) >> 16;
    return (unsigned short)r;
}
__device__ __forceinline__ float bf2f(unsigned short u) {
    unsigned x = ((unsigned)u) << 16;
    return __builtin_bit_cast(float, x);
}

// fragment-swizzled element address: matrix [rows][K cols] stored so that a
// wave's 16x32 MFMA fragment is contiguous: sw(r,k) =
//   tile(r>>4, k>>5) * 512 + lane((k>>3)&3, r&15) * 8 + (k&7)
__device__ __forceinline__ long long swidx(int r, int k, int kt /*=K>>5*/) {
    return ((long long)((r >> 4) * kt + (k >> 5)) << 9)
         + (((k >> 3) & 3) << 7) + ((r & 15) << 3) + (k & 7);
}

#define GLDS16(g, s)                                                        \
    __builtin_amdgcn_global_load_lds(                                       \
        (const __attribute__((address_space(1))) void*)(g),                 \
        (__attribute__((address_space(3))) void*)(s), 16, 0, 0)

// ---------------------------------------------------------------------------
// SWIZZLED register-direct bf16 MFMA GEMM (no LDS, no barriers).
// A (M x K) and B (N x K) in fragment-swizzled layout (see swidx).
// Wave tile 64x64: per BK=32 chunk each wave loads 4 A-frags + 4 B-frags
// (8 x 1KB coalesced) and issues 16 MFMAs -> 32.8 FLOP per byte-into-VGPR,
// 1.5x R1's 64x32 tile against the measured ~36 B/cy/CU vector-return wall
// (R1: 22.3 TB/s = 487 TF, arithmetic exact). Depth-2 register ring: R1
// showed prefetch depth is irrelevant once BW-bound. No barriers: avoids
// R2's collapse (barrier+vmcnt(0) serialization at 1-2 blocks/CU on the
// N=1024/2048 GEMMs of this network).
// Block = 2x2 waves = 128x128 tile.
// Outputs: Cf (fp32,+res row-major) | Cb (bf16 row-major) | Csw (bf16
// swizzled for the next GEMM, K_consumer = N) ; cols >= ctcol0 (Ct!=null)
// go transposed to Ct (attention V^T). M,N multiples of 128, kt=K/32 even.
// ---------------------------------------------------------------------------
__global__ __launch_bounds__(256) void gemm_sw_k(
    const unsigned short* __restrict__ Asw,
    const unsigned short* __restrict__ Bsw,
    const float* __restrict__ bias,
    const float* __restrict__ res,
    float* __restrict__ Cf,
    unsigned short* __restrict__ Cb,
    unsigned short* __restrict__ Csw,
    unsigned short* __restrict__ Ct, int ctcol0,
    int M, int N, int K, int ldC, int relu)
{
    const int t = threadIdx.x;
    const int w = t >> 6;
    const int l = t & 63;

    int bx = blockIdx.x, by = blockIdx.y;
    {
        int nbx = gridDim.x;
        int nb  = nbx * gridDim.y;
        if ((nb & 7) == 0) {
            int bid = by * nbx + bx;
            int nid = (bid & 7) * (nb >> 3) + (bid >> 3);
            by = nid / nbx;
            bx = nid - by * nbx;
        }
    }
    const int m0 = by * 128;
    const int n0 = bx * 128;
    const int r16 = l & 15;
    const int qb  = l >> 4;
    const int wm = w >> 1, wn = w & 1;
    const int kt = K >> 5;

    // fragment base pointers: contiguous 16B per lane
    const unsigned short* pa[4];
#pragma unroll
    for (int i = 0; i < 4; i++)
        pa[i] = Asw + ((long long)(((m0 >> 4) + 4 * wm + i) * kt) << 9) + l * 8;
    const unsigned short* pb[4];
#pragma unroll
    for (int j = 0; j < 4; j++)
        pb[j] = Bsw + ((long long)(((n0 >> 4) + 4 * wn + j) * kt) << 9) + l * 8;

    v4f acc[4][4];
#pragma unroll
    for (int i = 0; i < 4; i++)
#pragma unroll
        for (int j = 0; j < 4; j++) acc[i][j] = (v4f){0.f, 0.f, 0.f, 0.f};

    v8bf A0[4], A1[4], B0[4], B1[4];
    // prologue: chunk 0 -> buf0
#pragma unroll
    for (int i = 0; i < 4; i++) A0[i] = *(const v8bf*)(pa[i]);
#pragma unroll
    for (int j = 0; j < 4; j++) B0[j] = *(const v8bf*)(pb[j]);

    for (int s = 0; s < kt; s += 2) {
        {   // prefetch chunk s+1 -> buf1 (always valid: kt even, s <= kt-2)
            const long long o = (long long)(s + 1) << 9;
#pragma unroll
            for (int i = 0; i < 4; i++) A1[i] = *(const v8bf*)(pa[i] + o);
#pragma unroll
            for (int j = 0; j < 4; j++) B1[j] = *(const v8bf*)(pb[j] + o);
        }
#pragma unroll
        for (int i = 0; i < 4; i++)
#pragma unroll
            for (int j = 0; j < 4; j++)
                acc[i][j] = __builtin_amdgcn_mfma_f32_16x16x32_bf16(
                    A0[i], B0[j], acc[i][j], 0, 0, 0);
        if (s + 2 < kt) {   // prefetch chunk s+2 -> buf0
            const long long o = (long long)(s + 2) << 9;
#pragma unroll
            for (int i = 0; i < 4; i++) A0[i] = *(const v8bf*)(pa[i] + o);
#pragma unroll
            for (int j = 0; j < 4; j++) B0[j] = *(const v8bf*)(pb[j] + o);
        }
#pragma unroll
        for (int i = 0; i < 4; i++)
#pragma unroll
            for (int j = 0; j < 4; j++)
                acc[i][j] = __builtin_amdgcn_mfma_f32_16x16x32_bf16(
                    A1[i], B1[j], acc[i][j], 0, 0, 0);
    }

    float bv[4];
#pragma unroll
    for (int j = 0; j < 4; j++) bv[j] = bias[n0 + 64 * wn + 16 * j + r16];
    const int colbase = n0 + 64 * wn + r16;
    const int nt = N >> 5;
#pragma unroll
    for (int i = 0; i < 4; i++) {
        int rowb = m0 + 64 * wm + 16 * i + qb * 4;
#pragma unroll
        for (int j = 0; j < 4; j++) {
            int col = colbase + 16 * j;
            float v[4];
#pragma unroll
            for (int r = 0; r < 4; r++) v[r] = acc[i][j][r] + bv[j];
            if (Ct && col >= ctcol0) {
                ushort4 o;
                o.x = f2bfu(v[0]); o.y = f2bfu(v[1]);
                o.z = f2bfu(v[2]); o.w = f2bfu(v[3]);
                *(ushort4*)(Ct + ((long long)(rowb >> 10) << 20)
                            + (long long)(col - ctcol0) * 1024 + (rowb & 1023)) = o;
            } else if (Csw) {
#pragma unroll
                for (int r = 0; r < 4; r++) {
                    int row = rowb + r;
                    float vv = v[r];
                    if (relu) vv = fmaxf(vv, 0.f);
                    Csw[swidx(row, col, nt)] = f2bfu(vv);
                }
            } else {
#pragma unroll
                for (int r = 0; r < 4; r++) {
                    int row = rowb + r;
                    long long off = (long long)row * ldC + col;
                    float vv = v[r];
                    if (res)  vv += res[off];
                    if (relu) vv = fmaxf(vv, 0.f);
                    if (Cf) Cf[off] = vv;
                    if (Cb) ((unsigned short*)Cb)[off] = f2bfu(vv);
                }
            }
        }
    }
}

// ---------------------------------------------------------------------------
// LDS-staged GEMM (R5) — kept for the conv frontend (row-remapped A).
// ---------------------------------------------------------------------------
__global__ __launch_bounds__(256) void gemm_mfma_k(
    const __hip_bfloat16* __restrict__ A, int rpbA, long long bstrideA, int ldA,
    const __hip_bfloat16* __restrict__ B,
    const float* __restrict__ bias,
    const float* __restrict__ res,
    float* __restrict__ Cf,
    __hip_bfloat16* __restrict__ Cb,
    int M, int N, int K, int ldC, int relu)
{
    __shared__ __align__(16) __hip_bfloat16 As[2][8][64][8];
    __shared__ __align__(16) __hip_bfloat16 Bs[2][4][64][8];
    const int t  = threadIdx.x;
    const int w  = t >> 6;
    const int l  = t & 63;
    const int m0 = blockIdx.y * 128;
    const int n0 = blockIdx.x * 64;
    const int r16 = l & 15;
    const int qb  = l >> 4;
    const int wm = w >> 1, wn = w & 1;

    const __hip_bfloat16* gA[2];
#pragma unroll
    for (int tt = 0; tt < 2; tt++) {
        int arow = m0 + 16 * (2 * w + tt) + r16;
        gA[tt] = A + (long long)(arow / rpbA) * bstrideA
                   + (long long)(arow % rpbA) * ldA + qb * 8;
    }
    const __hip_bfloat16* gB = B + (long long)(n0 + 16 * w + r16) * K + qb * 8;

    v4f acc[4][2];
#pragma unroll
    for (int i = 0; i < 4; i++)
#pragma unroll
        for (int j = 0; j < 2; j++) acc[i][j] = (v4f){0.f, 0.f, 0.f, 0.f};

    GLDS16(gA[0], &As[0][2 * w + 0][0][0]);
    GLDS16(gA[1], &As[0][2 * w + 1][0][0]);
    GLDS16(gB,    &Bs[0][w][0][0]);
    __syncthreads();

    int cur = 0;
    for (int k0 = 32; k0 < K; k0 += 32) {
        v8bf af[4], bfr[2];
#pragma unroll
        for (int i = 0; i < 4; i++) af[i]  = *(const v8bf*)(&As[cur][4 * wm + i][l][0]);
#pragma unroll
        for (int j = 0; j < 2; j++) bfr[j] = *(const v8bf*)(&Bs[cur][2 * wn + j][l][0]);
        GLDS16(gA[0] + k0, &As[cur ^ 1][2 * w + 0][0][0]);
        GLDS16(gA[1] + k0, &As[cur ^ 1][2 * w + 1][0][0]);
        GLDS16(gB + k0,    &Bs[cur ^ 1][w][0][0]);
#pragma unroll
        for (int i = 0; i < 4; i++)
#pragma unroll
            for (int j = 0; j < 2; j++)
                acc[i][j] = __builtin_amdgcn_mfma_f32_16x16x32_bf16(
                    af[i], bfr[j], acc[i][j], 0, 0, 0);
        __syncthreads();
        cur ^= 1;
    }
    {
        v8bf af[4], bfr[2];
#pragma unroll
        for (int i = 0; i < 4; i++) af[i]  = *(const v8bf*)(&As[cur][4 * wm + i][l][0]);
#pragma unroll
        for (int j = 0; j < 2; j++) bfr[j] = *(const v8bf*)(&Bs[cur][2 * wn + j][l][0]);
#pragma unroll
        for (int i = 0; i < 4; i++)
#pragma unroll
            for (int j = 0; j < 2; j++)
                acc[i][j] = __builtin_amdgcn_mfma_f32_16x16x32_bf16(
                    af[i], bfr[j], acc[i][j], 0, 0, 0);
    }

    float bv[2];
#pragma unroll
    for (int j = 0; j < 2; j++) bv[j] = bias[n0 + 32 * wn + 16 * j + r16];
    const int colbase = n0 + 32 * wn + r16;
#pragma unroll
    for (int i = 0; i < 4; i++) {
        int rowb = m0 + 64 * wm + 16 * i + qb * 4;
#pragma unroll
        for (int j = 0; j < 2; j++) {
            int col = colbase + 16 * j;
#pragma unroll
            for (int r = 0; r < 4; r++) {
                int row = rowb + r;
                if (row >= M) continue;
                long long off = (long long)row * ldC + col;
                float vv = acc[i][j][r] + bv[j];
                if (res)  vv += res[off];
                if (relu) vv = fmaxf(vv, 0.f);
                if (Cf) Cf[off] = vv;
                if (Cb) ((unsigned short*)Cb)[off] = f2bfu(vv);
            }
        }
    }
}

// ---------------------------------------------------------------------------
// MFMA softsign attention. Output written in SWIZZLED layout (K=1024 -> 32).
// ---------------------------------------------------------------------------
__global__ __launch_bounds__(256) void attn_mfma_k(
    const unsigned short* __restrict__ QKV,
    const unsigned short* __restrict__ Vt,
    unsigned short* __restrict__ Osw)
{
    __shared__ __align__(16) unsigned short lds[25600];
    const int t = threadIdx.x, w = t >> 6, l = t & 63;
    const int bh = blockIdx.y, b = bh >> 4, h = bh & 15;
    const int s0 = blockIdx.x << 7;
    const int r16 = l & 15, q4 = l >> 4;
    const long long qrow0 = (long long)(b << 10) + s0;
    const int hoff = h << 6;

#pragma unroll
    for (int mi = 0; mi < 2; mi++)
#pragma unroll
        for (int kk = 0; kk < 2; kk++) {
            const unsigned short* g = QKV + (qrow0 + 32 * w + 16 * mi + r16) * 3072
                                      + hoff + 32 * kk + q4 * 8;
            GLDS16(g, &lds[(w * 4 + mi * 2 + kk) * 512]);
        }
    __syncthreads();
    v8bf qf[2][2];
#pragma unroll
    for (int mi = 0; mi < 2; mi++)
#pragma unroll
        for (int kk = 0; kk < 2; kk++)
            qf[mi][kk] = *(const v8bf*)&lds[(w * 4 + mi * 2 + kk) * 512 + l * 8];

    v4f oacc[2][4];
#pragma unroll
    for (int i = 0; i < 2; i++)
#pragma unroll
        for (int j = 0; j < 4; j++) oacc[i][j] = (v4f){0.f, 0.f, 0.f, 0.f};

    for (int t0 = 0; t0 < 1024; t0 += 64) {
#pragma unroll
        for (int rr = 0; rr < 2; rr++) {
            int r = 2 * w + rr, kk = r >> 2, j = r & 3;
            const unsigned short* gk = QKV
                + ((long long)(b << 10) + t0 + 16 * j + r16) * 3072
                + 1024 + hoff + 32 * kk + q4 * 8;
            GLDS16(gk, &lds[8192 + r * 512]);
            const unsigned short* gv = Vt + ((long long)b << 20)
                + (long long)(hoff + 16 * j + r16) * 1024 + t0 + 32 * kk + q4 * 8;
            GLDS16(gv, &lds[12288 + r * 512]);
        }
        __syncthreads();

        v8bf kf[2][4];
#pragma unroll
        for (int kk = 0; kk < 2; kk++)
#pragma unroll
            for (int j = 0; j < 4; j++)
                kf[kk][j] = *(const v8bf*)&lds[8192 + (kk * 4 + j) * 512 + l * 8];
        v4f sc[2][4];
#pragma unroll
        for (int i = 0; i < 2; i++)
#pragma unroll
            for (int j = 0; j < 4; j++) sc[i][j] = (v4f){0.f, 0.f, 0.f, 0.f};
#pragma unroll
        for (int kk = 0; kk < 2; kk++)
#pragma unroll
            for (int mi = 0; mi < 2; mi++)
#pragma unroll
                for (int j = 0; j < 4; j++)
                    sc[mi][j] = __builtin_amdgcn_mfma_f32_16x16x32_bf16(
                        qf[mi][kk], kf[kk][j], sc[mi][j], 0, 0, 0);

#pragma unroll
        for (int mi = 0; mi < 2; mi++)
#pragma unroll
            for (int j = 0; j < 4; j++)
#pragma unroll
                for (int r = 0; r < 4; r++) {
                    float v = sc[mi][j][r] * 0.125f;
                    float p = v * __builtin_amdgcn_rcpf(1.0f + fabsf(v));
                    lds[16384 + (32 * w + 16 * mi + q4 * 4 + r) * 72 + 16 * j + r16] = f2bfu(p);
                }

        v8bf pf[2][2], vf[2][4];
#pragma unroll
        for (int mi = 0; mi < 2; mi++)
#pragma unroll
            for (int kk = 0; kk < 2; kk++)
                pf[mi][kk] = *(const v8bf*)&lds[16384 + (32 * w + 16 * mi + r16) * 72
                                                + 32 * kk + q4 * 8];
#pragma unroll
        for (int kk = 0; kk < 2; kk++)
#pragma unroll
            for (int j = 0; j < 4; j++)
                vf[kk][j] = *(const v8bf*)&lds[12288 + (kk * 4 + j) * 512 + l * 8];
#pragma unroll
        for (int kk = 0; kk < 2; kk++)
#pragma unroll
            for (int mi = 0; mi < 2; mi++)
#pragma unroll
                for (int j = 0; j < 4; j++)
                    oacc[mi][j] = __builtin_amdgcn_mfma_f32_16x16x32_bf16(
                        pf[mi][kk], vf[kk][j], oacc[mi][j], 0, 0, 0);
        __syncthreads();
    }

#pragma unroll
    for (int mi = 0; mi < 2; mi++)
#pragma unroll
        for (int j = 0; j < 4; j++)
#pragma unroll
            for (int r = 0; r < 4; r++)
                lds[(32 * w + 16 * mi + q4 * 4 + r) * 72 + 16 * j + r16] =
                    f2bfu(oacc[mi][j][r]);
    __syncthreads();
    {
        int row = t >> 1, ch = (t & 1) << 5;
        int grow = (int)qrow0 + row;
#pragma unroll
        for (int i = 0; i < 4; i++) {
            int c0 = hoff + ch + 8 * i;
            v8us vv = *(const v8us*)&lds[row * 72 + ch + 8 * i];
            *(v8us*)(Osw + swidx(grow, c0, 32)) = vv;
        }
    }
}

// ---------------------------------------------------------------------------
// LayerNorm (torch-style), output bf16 in SWIZZLED layout (K=1024).
// ---------------------------------------------------------------------------
__global__ __launch_bounds__(256) void layernorm_k(
    const float* __restrict__ x, const float* __restrict__ w,
    const float* __restrict__ b, unsigned short* __restrict__ ysw)
{
    int row = blockIdx.x;
    int t = threadIdx.x;
    float4 v = ((const float4*)(x + ((long long)row << 10)))[t];
    float s = v.x + v.y + v.z + v.w;
#pragma unroll
    for (int o = 32; o; o >>= 1) s += __shfl_down(s, o);
    __shared__ float red[4];
    __shared__ float red2[4];
    int wid = t >> 6, lane = t & 63;
    if (lane == 0) red[wid] = s;
    __syncthreads();
    float mean = (red[0] + red[1] + red[2] + red[3]) * (1.0f / 1024.0f);
    float dx = v.x - mean, dy = v.y - mean, dz = v.z - mean, dw = v.w - mean;
    float sq = dx * dx + dy * dy + dz * dz + dw * dw;
#pragma unroll
    for (int o = 32; o; o >>= 1) sq += __shfl_down(sq, o);
    if (lane == 0) red2[wid] = sq;
    __syncthreads();
    float var = (red2[0] + red2[1] + red2[2] + red2[3]) * (1.0f / 1023.0f);
    float inv = 1.0f / (sqrtf(var) + 1e-6f);
    float4 W  = ((const float4*)w)[t];
    float4 Bv = ((const float4*)b)[t];
    ushort4 o;
    o.x = f2bfu(W.x * (dx * inv) + Bv.x);
    o.y = f2bfu(W.y * (dy * inv) + Bv.y);
    o.z = f2bfu(W.z * (dz * inv) + Bv.z);
    o.w = f2bfu(W.w * (dw * inv) + Bv.w);
    int c0 = t << 2;
    *(ushort4*)(ysw + swidx(row, c0, 32)) = o;
}

// ---------------------------------------------------------------------------
__global__ __launch_bounds__(256) void add_pos_k(float* __restrict__ h)
{
    int idx = blockIdx.x * 256 + threadIdx.x;
    int d = idx & 1023;
    int s = (idx >> 10) & 1023;
    int e = d & ~1;
    float div = expf(-9.210340371976184f * (float)e * (1.0f / 1024.0f));
    float arg = (float)s * div;
    float pe = (d & 1) ? cosf(arg) : sinf(arg);
    h[idx] += pe;
}

__global__ __launch_bounds__(256) void convert_k(
    const float* __restrict__ src, unsigned short* __restrict__ dst, int n4)
{
    int i = blockIdx.x * 256 + threadIdx.x;
    if (i >= n4) return;
    float4 v = ((const float4*)src)[i];
    ushort4 o;
    o.x = f2bfu(v.x); o.y = f2bfu(v.y); o.z = f2bfu(v.z); o.w = f2bfu(v.w);
    ((ushort4*)dst)[i] = o;
}

// Layer weights fp32 row-major -> bf16 SWIZZLED, all 6 matrices, one launch.
// dst layout (us): q,k,v,o (1M each), f1 (2M), f2 (2M) — contiguous.
__global__ __launch_bounds__(256) void convert_layer_sw_k(
    const float* __restrict__ q, const float* __restrict__ k,
    const float* __restrict__ v, const float* __restrict__ o,
    const float* __restrict__ f1, const float* __restrict__ f2,
    unsigned short* __restrict__ dst)
{
    int idx = blockIdx.x * 256 + threadIdx.x;   // float4 index, [0, 2M)
    const float* src;
    unsigned short* db;
    int Ksh, rf;
    if (idx < 0x100000) {
        int region = idx >> 18;
        rf = idx & 0x3FFFF;
        src = (region == 0) ? q : (region == 1) ? k : (region == 2) ? v : o;
        db = dst + ((long long)region << 20);
        Ksh = 10;
    } else if (idx < 0x180000) {
        rf = idx - 0x100000; src = f1; db = dst + (4LL << 20); Ksh = 10;
    } else {
        rf = idx - 0x180000; src = f2; db = dst + (6LL << 20); Ksh = 11;
    }
    float4 vv = ((const float4*)src)[rf];
    int flatf = rf << 2;
    int n  = flatf >> Ksh;
    int k0 = flatf & ((1 << Ksh) - 1);
    ushort4 ov;
    ov.x = f2bfu(vv.x); ov.y = f2bfu(vv.y); ov.z = f2bfu(vv.z); ov.w = f2bfu(vv.w);
    *(ushort4*)(db + swidx(n, k0, 1 << (Ksh - 5))) = ov;
}

__global__ __launch_bounds__(256) void concat3_k(
    const float* __restrict__ a, const float* __restrict__ b,
    const float* __restrict__ c, float* __restrict__ o)
{
    int i = blockIdx.x * 256 + threadIdx.x;
    o[i] = (i < 1024) ? a[i] : ((i < 2048) ? b[i - 1024] : c[i - 2048]);
}

__global__ __launch_bounds__(256) void reorder_w_k(
    const float* __restrict__ src, unsigned short* __restrict__ dst, int OC, int IC)
{
    int idx = blockIdx.x * 256 + threadIdx.x;
    if (idx >= OC * IC * 3) return;
    int k  = idx % 3;
    int ic = (idx / 3) % IC;
    int oc = idx / (3 * IC);
    dst[(oc * 3 + k) * IC + ic] = f2bfu(src[idx]);
}

// meanpool split: 256-block partial pass (16 rows each, all 1024 d) then a
// 16-block reduce. Old single-pass version ran on only 16 CUs pulling 16 MB.
__global__ __launch_bounds__(256) void meanpool_part_k(
    const float* __restrict__ h, float* __restrict__ part)
{
    int g = blockIdx.x;                 // g = b*64 + rblk
    int b = g >> 6, rblk = g & 63;
    const float4* base = (const float4*)(h + ((long long)b << 20)
                                           + ((long long)(rblk * 16) << 10));
    float4 s = {0.f, 0.f, 0.f, 0.f};
#pragma unroll
    for (int i = 0; i < 16; i++) {
        float4 v = base[i * 256 + threadIdx.x];
        s.x += v.x; s.y += v.y; s.z += v.z; s.w += v.w;
    }
    ((float4*)part)[g * 256 + threadIdx.x] = s;
}

__global__ __launch_bounds__(256) void meanpool_red_k(
    const float* __restrict__ part, float* __restrict__ pooled)
{
    int idx = blockIdx.x * 256 + threadIdx.x;   // 4096: b = idx>>10, d = idx&1023
    int b = idx >> 10, d = idx & 1023;
    const float* p = part + ((long long)(b * 64) << 10) + d;
    float s = 0.f;
#pragma unroll 8
    for (int r = 0; r < 64; r++) s += p[r << 10];
    pooled[idx] = s * (1.0f / 1024.0f);
}

__global__ __launch_bounds__(256) void fc_k(
    const float* __restrict__ p, const float* __restrict__ w,
    const float* __restrict__ fb, float* __restrict__ out)
{
    int b = blockIdx.x, t = threadIdx.x;
    float s = 0.f;
    for (int i = t; i < 1024; i += 256) s += p[(b << 10) + i] * w[i];
#pragma unroll
    for (int o = 32; o; o >>= 1) s += __shfl_down(s, o);
    __shared__ float red[4];
    if ((t & 63) == 0) red[t >> 6] = s;
    __syncthreads();
    if (t == 0) out[b] = red[0] + red[1] + red[2] + red[3] + fb[0];
}

// ---------------------------------------------------------------------------
extern "C" void kernel_launch(void* const* d_in, const int* in_sizes, int n_in,
                              void* d_out, int out_size, void* d_ws, size_t ws_size,
                              hipStream_t stream)
{
    const float* x    = (const float*)d_in[0];
    const float* c1w  = (const float*)d_in[1];
    const float* c1b  = (const float*)d_in[2];
    const float* c2w  = (const float*)d_in[3];
    const float* c2b  = (const float*)d_in[4];
    const float* lnAw = (const float*)d_in[5];
    const float* lnAb = (const float*)d_in[6];
    const float* qw   = (const float*)d_in[7];
    const float* qbi  = (const float*)d_in[8];
    const float* kw   = (const float*)d_in[9];
    const float* kbi  = (const float*)d_in[10];
    const float* vw   = (const float*)d_in[11];
    const float* vbi  = (const float*)d_in[12];
    const float* ow   = (const float*)d_in[13];
    const float* obi  = (const float*)d_in[14];
    const float* lnBw = (const float*)d_in[15];
    const float* lnBb = (const float*)d_in[16];
    const float* f1w  = (const float*)d_in[17];
    const float* f1b  = (const float*)d_in[18];
    const float* f2w  = (const float*)d_in[19];
    const float* f2b  = (const float*)d_in[20];
    const float* fcw  = (const float*)d_in[21];
    const float* fcb  = (const float*)d_in[22];
    float* out = (float*)d_out;

    float* ws = (float*)d_ws;
    typedef __hip_bfloat16 bf;
    typedef unsigned short us;
    float* h    = ws;                          // 4,194,304 f
    us* hn_b    = (us*)(ws + 4194304);         // 4M us (swizzled activations)
    us* qkv_b   = (us*)(ws + 6291456);         // [4096][3072] us row-major
    us* ff_b    = qkv_b;                       // [4096][2048] swizzled overlay
    us* wq_b    = (us*)(ws + 12582912);        // swizzled: q,k,v,o,f1,f2
    us* wo_b    = (us*)(ws + 14155776);
    us* wf1_b   = (us*)(ws + 14680064);
    us* wf2_b   = (us*)(ws + 15728640);
    us* xb      = (us*)(ws + 16777216);
    us* h1b     = (us*)(ws + 16912896);
    us* w1t_b   = (us*)(ws + 17963520);
    us* w2t_b   = (us*)(ws + 18012672);
    float* pooled = ws + 18799104;             // 4,096 f
    us* Vt      = (us*)(ws + 18803200);        // [4][1024 d][1024 t] us
    float* bqkv = ws + 20900352;               // 3,072 f
    float* mp_part = ws + 20903424;            // 262,144 f (meanpool partials)

    convert_k<<<dim3(257), 256, 0, stream>>>(x, xb, 65792);
    reorder_w_k<<<dim3(384),  256, 0, stream>>>(c1w, w1t_b, 512, 64);
    reorder_w_k<<<dim3(6144), 256, 0, stream>>>(c2w, w2t_b, 1024, 512);

    // conv1: M=4104, N=512, K=192 (LDS-staged kernel, row-remapped A)
    gemm_mfma_k<<<dim3(8, 33), 256, 0, stream>>>(
        (const bf*)xb, 1026, 1028LL * 64, 64, (const bf*)w1t_b,
        c1b, nullptr, nullptr, (bf*)h1b, 4104, 512, 192, 512, 0);
    // conv2: M=4096, N=1024, K=1536
    gemm_mfma_k<<<dim3(16, 32), 256, 0, stream>>>(
        (const bf*)h1b, 1024, 1026LL * 512, 512, (const bf*)w2t_b,
        c2b, nullptr, h, nullptr, 4096, 1024, 1536, 1024, 0);
    add_pos_k<<<dim3(16384), 256, 0, stream>>>(h);

    for (int l = 0; l < 4; l++) {
        long long wo  = (long long)l * 1048576;
        long long wo2 = (long long)l * 2097152;
        convert_layer_sw_k<<<dim3(8192), 256, 0, stream>>>(
            qw + wo, kw + wo, vw + wo, ow + wo, f1w + wo2, f2w + wo2, wq_b);
        concat3_k<<<dim3(12), 256, 0, stream>>>(qbi + l * 1024, kbi + l * 1024,
                                                vbi + l * 1024, bqkv);

        layernorm_k<<<dim3(4096), 256, 0, stream>>>(h, lnAw + l * 1024, lnAb + l * 1024, hn_b);
        // fused QKV: N=3072; Q,K swizzled to qkv_b; V transposed to Vt
        gemm_sw_k<<<dim3(24, 32), 256, 0, stream>>>(
            hn_b, wq_b, bqkv, nullptr, nullptr, qkv_b, nullptr, Vt, 2048,
            4096, 3072, 1024, 3072, 0);
        attn_mfma_k<<<dim3(8, 64), 256, 0, stream>>>(qkv_b, Vt, hn_b);
        // O-proj: out fp32 h += res
        gemm_sw_k<<<dim3(8, 32), 256, 0, stream>>>(
            hn_b, wo_b, obi + l * 1024, h, h, nullptr, nullptr, nullptr, 0,
            4096, 1024, 1024, 1024, 0);
        layernorm_k<<<dim3(4096), 256, 0, stream>>>(h, lnBw + l * 1024, lnBb + l * 1024, hn_b);
        // FF1: out swizzled bf16 (+relu)
        gemm_sw_k<<<dim3(16, 32), 256, 0, stream>>>(
            hn_b, wf1_b, f1b + l * 2048, nullptr, nullptr, nullptr, ff_b, nullptr, 0,
            4096, 2048, 1024, 2048, 1);
        // FF2: out fp32 h += res
        gemm_sw_k<<<dim3(8, 32), 256, 0, stream>>>(
            ff_b, wf2_b, f2b + l * 1024, h, h, nullptr, nullptr, nullptr, 0,
            4096, 1024, 2048, 1024, 0);
    }

    meanpool_part_k<<<dim3(256), 256, 0, stream>>>(h, mp_part);
    meanpool_red_k<<<dim3(16), 256, 0, stream>>>(mp_part, pooled);
    fc_k<<<dim3(4), 256, 0, stream>>>(pooled, fcw, fcb, out);
}

// Round 4
// 1143.292 us; speedup vs baseline: 1.1189x; 1.0185x over previous
//
#include <hip/hip_runtime.h>
#include <hip/hip_bf16.h>
#include <math.h>

// ---------------------------------------------------------------------------
// helpers
// ---------------------------------------------------------------------------
typedef __bf16 v8bf __attribute__((ext_vector_type(8)));
typedef float  v4f  __attribute__((ext_vector_type(4)));
typedef unsigned short v8us __attribute__((ext_vector_type(8)));

__device__ __forceinline__ unsigned short f2bfu(float f) {
    unsigned u = __builtin_bit_cast(unsigned, f);
    unsigned r = (u + 0x7fffu + ((u >> 16) & 1u)) >> 16;
    return (unsigned short)r;
}
__device__ __forceinline__ float bf2f(unsigned short u) {
    unsigned x = ((unsigned)u) << 16;
    return __builtin_bit_cast(float, x);
}

// fragment-swizzled element address: matrix [rows][K cols] stored so that a
// wave's 16x32 MFMA fragment is contiguous: sw(r,k) =
//   tile(r>>4, k>>5) * 512 + lane((k>>3)&3, r&15) * 8 + (k&7)
__device__ __forceinline__ long long swidx(int r, int k, int kt /*=K>>5*/) {
    return ((long long)((r >> 4) * kt + (k >> 5)) << 9)
         + (((k >> 3) & 3) << 7) + ((r & 15) << 3) + (k & 7);
}

#define GLDS16(g, s)                                                        \
    __builtin_amdgcn_global_load_lds(                                       \
        (const __attribute__((address_space(1))) void*)(g),                 \
        (__attribute__((address_space(3))) void*)(s), 16, 0, 0)

// ---------------------------------------------------------------------------
// SWIZZLED register-direct bf16 MFMA GEMM (no LDS, no barriers).
// A (M x K) and B (N x K) in fragment-swizzled layout (see swidx).
// ONE WAVE PER BLOCK (64 threads), wave tile 64x64.
// K-loop: branch-free depth-4 register ring, prefetch distance 3 chunks.
// R1-R3 post-mortem: all prior rings had runtime branches (or copy-backs)
// around the loads -> path-dependent outstanding-load counts -> compiler
// emits conservative vmcnt waits -> one full memory latency (~1300cy) per
// 8KB chunk, MfmaUtil pinned at 18%. This body is straight-line with
// literal ring indices and a peeled epilogue, so counted vmcnt(N) applies
// and loads issued 3 phases (~250cy+) earlier are complete when consumed.
// 1-wave blocks: wave tile is self-contained, so 4-wave blocks only
// coarsened the grid (O-proj/FF2 were 256 blocks = 1 block/CU).
// Now QKV=3072, FF1=2048, O/FF2=1024 blocks. __launch_bounds__(64,2)
// pins 2 waves/SIMD (VGPR<=256; ring 128 + acc 64 + addr ~24).
// Outputs: Cf (fp32,+res row-major) | Cb (bf16 row-major) | Csw (bf16
// swizzled for the next GEMM, K_consumer = N) ; cols >= ctcol0 (Ct!=null)
// go transposed to Ct (attention V^T). M,N multiples of 64, kt=K/32
// a multiple of 4 and >= 8 (kt = 32 or 64 here).
// ---------------------------------------------------------------------------
#define LOAD_CHUNK(R, C) do {                                               \
    const long long o_ = (long long)(C) << 9;                               \
    _Pragma("unroll")                                                       \
    for (int i_ = 0; i_ < 4; i_++) Ab[R][i_] = *(const v8bf*)(pa[i_] + o_); \
    _Pragma("unroll")                                                       \
    for (int j_ = 0; j_ < 4; j_++) Bb[R][j_] = *(const v8bf*)(pb[j_] + o_); \
} while (0)

#define MFMA_CHUNK(R) do {                                                  \
    _Pragma("unroll")                                                       \
    for (int i_ = 0; i_ < 4; i_++)                                          \
    _Pragma("unroll")                                                       \
    for (int j_ = 0; j_ < 4; j_++)                                          \
        acc[i_][j_] = __builtin_amdgcn_mfma_f32_16x16x32_bf16(              \
            Ab[R][i_], Bb[R][j_], acc[i_][j_], 0, 0, 0);                    \
} while (0)

__global__ __launch_bounds__(64, 2) void gemm_sw_k(
    const unsigned short* __restrict__ Asw,
    const unsigned short* __restrict__ Bsw,
    const float* __restrict__ bias,
    const float* __restrict__ res,
    float* __restrict__ Cf,
    unsigned short* __restrict__ Cb,
    unsigned short* __restrict__ Csw,
    unsigned short* __restrict__ Ct, int ctcol0,
    int M, int N, int K, int ldC, int relu)
{
    const int l = threadIdx.x;

    int bx = blockIdx.x, by = blockIdx.y;
    {
        int nbx = gridDim.x;
        int nb  = nbx * gridDim.y;
        if ((nb & 7) == 0) {
            int bid = by * nbx + bx;
            int nid = (bid & 7) * (nb >> 3) + (bid >> 3);
            by = nid / nbx;
            bx = nid - by * nbx;
        }
    }
    const int m0 = by * 64;
    const int n0 = bx * 64;
    const int r16 = l & 15;
    const int qb  = l >> 4;
    const int kt = K >> 5;

    // fragment base pointers: contiguous 16B per lane
    const unsigned short* pa[4];
#pragma unroll
    for (int i = 0; i < 4; i++)
        pa[i] = Asw + ((long long)(((m0 >> 4) + i) * kt) << 9) + l * 8;
    const unsigned short* pb[4];
#pragma unroll
    for (int j = 0; j < 4; j++)
        pb[j] = Bsw + ((long long)(((n0 >> 4) + j) * kt) << 9) + l * 8;

    v4f acc[4][4];
#pragma unroll
    for (int i = 0; i < 4; i++)
#pragma unroll
        for (int j = 0; j < 4; j++) acc[i][j] = (v4f){0.f, 0.f, 0.f, 0.f};

    v8bf Ab[4][4], Bb[4][4];

    // prologue: chunks 0,1,2 -> rings 0,1,2
    LOAD_CHUNK(0, 0);
    LOAD_CHUNK(1, 1);
    LOAD_CHUNK(2, 2);

    // steady state: straight-line, no branches, literal ring indices.
    int s = 0;
    for (; s < kt - 4; s += 4) {
        LOAD_CHUNK(3, s + 3); MFMA_CHUNK(0);
        LOAD_CHUNK(0, s + 4); MFMA_CHUNK(1);
        LOAD_CHUNK(1, s + 5); MFMA_CHUNK(2);
        LOAD_CHUNK(2, s + 6); MFMA_CHUNK(3);
    }
    // epilogue: s == kt-4; rings hold kt-4,kt-3,kt-2; load last chunk.
    LOAD_CHUNK(3, kt - 1);
    MFMA_CHUNK(0); MFMA_CHUNK(1); MFMA_CHUNK(2); MFMA_CHUNK(3);

    float bv[4];
#pragma unroll
    for (int j = 0; j < 4; j++) bv[j] = bias[n0 + 16 * j + r16];
    const int colbase = n0 + r16;
    const int nt = N >> 5;
#pragma unroll
    for (int i = 0; i < 4; i++) {
        int rowb = m0 + 16 * i + qb * 4;
#pragma unroll
        for (int j = 0; j < 4; j++) {
            int col = colbase + 16 * j;
            float v[4];
#pragma unroll
            for (int r = 0; r < 4; r++) v[r] = acc[i][j][r] + bv[j];
            if (Ct && col >= ctcol0) {
                ushort4 o;
                o.x = f2bfu(v[0]); o.y = f2bfu(v[1]);
                o.z = f2bfu(v[2]); o.w = f2bfu(v[3]);
                *(ushort4*)(Ct + ((long long)(rowb >> 10) << 20)
                            + (long long)(col - ctcol0) * 1024 + (rowb & 1023)) = o;
            } else if (Csw) {
#pragma unroll
                for (int r = 0; r < 4; r++) {
                    int row = rowb + r;
                    float vv = v[r];
                    if (relu) vv = fmaxf(vv, 0.f);
                    Csw[swidx(row, col, nt)] = f2bfu(vv);
                }
            } else {
#pragma unroll
                for (int r = 0; r < 4; r++) {
                    int row = rowb + r;
                    long long off = (long long)row * ldC + col;
                    float vv = v[r];
                    if (res)  vv += res[off];
                    if (relu) vv = fmaxf(vv, 0.f);
                    if (Cf) Cf[off] = vv;
                    if (Cb) ((unsigned short*)Cb)[off] = f2bfu(vv);
                }
            }
        }
    }
}

// ---------------------------------------------------------------------------
// LDS-staged GEMM (R5) — kept for the conv frontend (row-remapped A).
// ---------------------------------------------------------------------------
__global__ __launch_bounds__(256) void gemm_mfma_k(
    const __hip_bfloat16* __restrict__ A, int rpbA, long long bstrideA, int ldA,
    const __hip_bfloat16* __restrict__ B,
    const float* __restrict__ bias,
    const float* __restrict__ res,
    float* __restrict__ Cf,
    __hip_bfloat16* __restrict__ Cb,
    int M, int N, int K, int ldC, int relu)
{
    __shared__ __align__(16) __hip_bfloat16 As[2][8][64][8];
    __shared__ __align__(16) __hip_bfloat16 Bs[2][4][64][8];
    const int t  = threadIdx.x;
    const int w  = t >> 6;
    const int l  = t & 63;
    const int m0 = blockIdx.y * 128;
    const int n0 = blockIdx.x * 64;
    const int r16 = l & 15;
    const int qb  = l >> 4;
    const int wm = w >> 1, wn = w & 1;

    const __hip_bfloat16* gA[2];
#pragma unroll
    for (int tt = 0; tt < 2; tt++) {
        int arow = m0 + 16 * (2 * w + tt) + r16;
        gA[tt] = A + (long long)(arow / rpbA) * bstrideA
                   + (long long)(arow % rpbA) * ldA + qb * 8;
    }
    const __hip_bfloat16* gB = B + (long long)(n0 + 16 * w + r16) * K + qb * 8;

    v4f acc[4][2];
#pragma unroll
    for (int i = 0; i < 4; i++)
#pragma unroll
        for (int j = 0; j < 2; j++) acc[i][j] = (v4f){0.f, 0.f, 0.f, 0.f};

    GLDS16(gA[0], &As[0][2 * w + 0][0][0]);
    GLDS16(gA[1], &As[0][2 * w + 1][0][0]);
    GLDS16(gB,    &Bs[0][w][0][0]);
    __syncthreads();

    int cur = 0;
    for (int k0 = 32; k0 < K; k0 += 32) {
        v8bf af[4], bfr[2];
#pragma unroll
        for (int i = 0; i < 4; i++) af[i]  = *(const v8bf*)(&As[cur][4 * wm + i][l][0]);
#pragma unroll
        for (int j = 0; j < 2; j++) bfr[j] = *(const v8bf*)(&Bs[cur][2 * wn + j][l][0]);
        GLDS16(gA[0] + k0, &As[cur ^ 1][2 * w + 0][0][0]);
        GLDS16(gA[1] + k0, &As[cur ^ 1][2 * w + 1][0][0]);
        GLDS16(gB + k0,    &Bs[cur ^ 1][w][0][0]);
#pragma unroll
        for (int i = 0; i < 4; i++)
#pragma unroll
            for (int j = 0; j < 2; j++)
                acc[i][j] = __builtin_amdgcn_mfma_f32_16x16x32_bf16(
                    af[i], bfr[j], acc[i][j], 0, 0, 0);
        __syncthreads();
        cur ^= 1;
    }
    {
        v8bf af[4], bfr[2];
#pragma unroll
        for (int i = 0; i < 4; i++) af[i]  = *(const v8bf*)(&As[cur][4 * wm + i][l][0]);
#pragma unroll
        for (int j = 0; j < 2; j++) bfr[j] = *(const v8bf*)(&Bs[cur][2 * wn + j][l][0]);
#pragma unroll
        for (int i = 0; i < 4; i++)
#pragma unroll
            for (int j = 0; j < 2; j++)
                acc[i][j] = __builtin_amdgcn_mfma_f32_16x16x32_bf16(
                    af[i], bfr[j], acc[i][j], 0, 0, 0);
    }

    float bv[2];
#pragma unroll
    for (int j = 0; j < 2; j++) bv[j] = bias[n0 + 32 * wn + 16 * j + r16];
    const int colbase = n0 + 32 * wn + r16;
#pragma unroll
    for (int i = 0; i < 4; i++) {
        int rowb = m0 + 64 * wm + 16 * i + qb * 4;
#pragma unroll
        for (int j = 0; j < 2; j++) {
            int col = colbase + 16 * j;
#pragma unroll
            for (int r = 0; r < 4; r++) {
                int row = rowb + r;
                if (row >= M) continue;
                long long off = (long long)row * ldC + col;
                float vv = acc[i][j][r] + bv[j];
                if (res)  vv += res[off];
                if (relu) vv = fmaxf(vv, 0.f);
                if (Cf) Cf[off] = vv;
                if (Cb) ((unsigned short*)Cb)[off] = f2bfu(vv);
            }
        }
    }
}

// ---------------------------------------------------------------------------
// MFMA softsign attention. Output written in SWIZZLED layout (K=1024 -> 32).
// ---------------------------------------------------------------------------
__global__ __launch_bounds__(256) void attn_mfma_k(
    const unsigned short* __restrict__ QKV,
    const unsigned short* __restrict__ Vt,
    unsigned short* __restrict__ Osw)
{
    __shared__ __align__(16) unsigned short lds[25600];
    const int t = threadIdx.x, w = t >> 6, l = t & 63;
    const int bh = blockIdx.y, b = bh >> 4, h = bh & 15;
    const int s0 = blockIdx.x << 7;
    const int r16 = l & 15, q4 = l >> 4;
    const long long qrow0 = (long long)(b << 10) + s0;
    const int hoff = h << 6;

#pragma unroll
    for (int mi = 0; mi < 2; mi++)
#pragma unroll
        for (int kk = 0; kk < 2; kk++) {
            const unsigned short* g = QKV + (qrow0 + 32 * w + 16 * mi + r16) * 3072
                                      + hoff + 32 * kk + q4 * 8;
            GLDS16(g, &lds[(w * 4 + mi * 2 + kk) * 512]);
        }
    __syncthreads();
    v8bf qf[2][2];
#pragma unroll
    for (int mi = 0; mi < 2; mi++)
#pragma unroll
        for (int kk = 0; kk < 2; kk++)
            qf[mi][kk] = *(const v8bf*)&lds[(w * 4 + mi * 2 + kk) * 512 + l * 8];

    v4f oacc[2][4];
#pragma unroll
    for (int i = 0; i < 2; i++)
#pragma unroll
        for (int j = 0; j < 4; j++) oacc[i][j] = (v4f){0.f, 0.f, 0.f, 0.f};

    for (int t0 = 0; t0 < 1024; t0 += 64) {
#pragma unroll
        for (int rr = 0; rr < 2; rr++) {
            int r = 2 * w + rr, kk = r >> 2, j = r & 3;
            const unsigned short* gk = QKV
                + ((long long)(b << 10) + t0 + 16 * j + r16) * 3072
                + 1024 + hoff + 32 * kk + q4 * 8;
            GLDS16(gk, &lds[8192 + r * 512]);
            const unsigned short* gv = Vt + ((long long)b << 20)
                + (long long)(hoff + 16 * j + r16) * 1024 + t0 + 32 * kk + q4 * 8;
            GLDS16(gv, &lds[12288 + r * 512]);
        }
        __syncthreads();

        v8bf kf[2][4];
#pragma unroll
        for (int kk = 0; kk < 2; kk++)
#pragma unroll
            for (int j = 0; j < 4; j++)
                kf[kk][j] = *(const v8bf*)&lds[8192 + (kk * 4 + j) * 512 + l * 8];
        v4f sc[2][4];
#pragma unroll
        for (int i = 0; i < 2; i++)
#pragma unroll
            for (int j = 0; j < 4; j++) sc[i][j] = (v4f){0.f, 0.f, 0.f, 0.f};
#pragma unroll
        for (int kk = 0; kk < 2; kk++)
#pragma unroll
            for (int mi = 0; mi < 2; mi++)
#pragma unroll
                for (int j = 0; j < 4; j++)
                    sc[mi][j] = __builtin_amdgcn_mfma_f32_16x16x32_bf16(
                        qf[mi][kk], kf[kk][j], sc[mi][j], 0, 0, 0);

#pragma unroll
        for (int mi = 0; mi < 2; mi++)
#pragma unroll
            for (int j = 0; j < 4; j++)
#pragma unroll
                for (int r = 0; r < 4; r++) {
                    float v = sc[mi][j][r] * 0.125f;
                    float p = v * __builtin_amdgcn_rcpf(1.0f + fabsf(v));
                    lds[16384 + (32 * w + 16 * mi + q4 * 4 + r) * 72 + 16 * j + r16] = f2bfu(p);
                }

        v8bf pf[2][2], vf[2][4];
#pragma unroll
        for (int mi = 0; mi < 2; mi++)
#pragma unroll
            for (int kk = 0; kk < 2; kk++)
                pf[mi][kk] = *(const v8bf*)&lds[16384 + (32 * w + 16 * mi + r16) * 72
                                                + 32 * kk + q4 * 8];
#pragma unroll
        for (int kk = 0; kk < 2; kk++)
#pragma unroll
            for (int j = 0; j < 4; j++)
                vf[kk][j] = *(const v8bf*)&lds[12288 + (kk * 4 + j) * 512 + l * 8];
#pragma unroll
        for (int kk = 0; kk < 2; kk++)
#pragma unroll
            for (int mi = 0; mi < 2; mi++)
#pragma unroll
                for (int j = 0; j < 4; j++)
                    oacc[mi][j] = __builtin_amdgcn_mfma_f32_16x16x32_bf16(
                        pf[mi][kk], vf[kk][j], oacc[mi][j], 0, 0, 0);
        __syncthreads();
    }

#pragma unroll
    for (int mi = 0; mi < 2; mi++)
#pragma unroll
        for (int j = 0; j < 4; j++)
#pragma unroll
            for (int r = 0; r < 4; r++)
                lds[(32 * w + 16 * mi + q4 * 4 + r) * 72 + 16 * j + r16] =
                    f2bfu(oacc[mi][j][r]);
    __syncthreads();
    {
        int row = t >> 1, ch = (t & 1) << 5;
        int grow = (int)qrow0 + row;
#pragma unroll
        for (int i = 0; i < 4; i++) {
            int c0 = hoff + ch + 8 * i;
            v8us vv = *(const v8us*)&lds[row * 72 + ch + 8 * i];
            *(v8us*)(Osw + swidx(grow, c0, 32)) = vv;
        }
    }
}

// ---------------------------------------------------------------------------
// LayerNorm (torch-style), output bf16 in SWIZZLED layout (K=1024).
// ---------------------------------------------------------------------------
__global__ __launch_bounds__(256) void layernorm_k(
    const float* __restrict__ x, const float* __restrict__ w,
    const float* __restrict__ b, unsigned short* __restrict__ ysw)
{
    int row = blockIdx.x;
    int t = threadIdx.x;
    float4 v = ((const float4*)(x + ((long long)row << 10)))[t];
    float s = v.x + v.y + v.z + v.w;
#pragma unroll
    for (int o = 32; o; o >>= 1) s += __shfl_down(s, o);
    __shared__ float red[4];
    __shared__ float red2[4];
    int wid = t >> 6, lane = t & 63;
    if (lane == 0) red[wid] = s;
    __syncthreads();
    float mean = (red[0] + red[1] + red[2] + red[3]) * (1.0f / 1024.0f);
    float dx = v.x - mean, dy = v.y - mean, dz = v.z - mean, dw = v.w - mean;
    float sq = dx * dx + dy * dy + dz * dz + dw * dw;
#pragma unroll
    for (int o = 32; o; o >>= 1) sq += __shfl_down(sq, o);
    if (lane == 0) red2[wid] = sq;
    __syncthreads();
    float var = (red2[0] + red2[1] + red2[2] + red2[3]) * (1.0f / 1023.0f);
    float inv = 1.0f / (sqrtf(var) + 1e-6f);
    float4 W  = ((const float4*)w)[t];
    float4 Bv = ((const float4*)b)[t];
    ushort4 o;
    o.x = f2bfu(W.x * (dx * inv) + Bv.x);
    o.y = f2bfu(W.y * (dy * inv) + Bv.y);
    o.z = f2bfu(W.z * (dz * inv) + Bv.z);
    o.w = f2bfu(W.w * (dw * inv) + Bv.w);
    int c0 = t << 2;
    *(ushort4*)(ysw + swidx(row, c0, 32)) = o;
}

// ---------------------------------------------------------------------------
__global__ __launch_bounds__(256) void add_pos_k(float* __restrict__ h)
{
    int idx = blockIdx.x * 256 + threadIdx.x;
    int d = idx & 1023;
    int s = (idx >> 10) & 1023;
    int e = d & ~1;
    float div = expf(-9.210340371976184f * (float)e * (1.0f / 1024.0f));
    float arg = (float)s * div;
    float pe = (d & 1) ? cosf(arg) : sinf(arg);
    h[idx] += pe;
}

__global__ __launch_bounds__(256) void convert_k(
    const float* __restrict__ src, unsigned short* __restrict__ dst, int n4)
{
    int i = blockIdx.x * 256 + threadIdx.x;
    if (i >= n4) return;
    float4 v = ((const float4*)src)[i];
    ushort4 o;
    o.x = f2bfu(v.x); o.y = f2bfu(v.y); o.z = f2bfu(v.z); o.w = f2bfu(v.w);
    ((ushort4*)dst)[i] = o;
}

// Layer weights fp32 row-major -> bf16 SWIZZLED, all 6 matrices, one launch.
// dst layout (us): q,k,v,o (1M each), f1 (2M), f2 (2M) — contiguous.
__global__ __launch_bounds__(256) void convert_layer_sw_k(
    const float* __restrict__ q, const float* __restrict__ k,
    const float* __restrict__ v, const float* __restrict__ o,
    const float* __restrict__ f1, const float* __restrict__ f2,
    unsigned short* __restrict__ dst)
{
    int idx = blockIdx.x * 256 + threadIdx.x;   // float4 index, [0, 2M)
    const float* src;
    unsigned short* db;
    int Ksh, rf;
    if (idx < 0x100000) {
        int region = idx >> 18;
        rf = idx & 0x3FFFF;
        src = (region == 0) ? q : (region == 1) ? k : (region == 2) ? v : o;
        db = dst + ((long long)region << 20);
        Ksh = 10;
    } else if (idx < 0x180000) {
        rf = idx - 0x100000; src = f1; db = dst + (4LL << 20); Ksh = 10;
    } else {
        rf = idx - 0x180000; src = f2; db = dst + (6LL << 20); Ksh = 11;
    }
    float4 vv = ((const float4*)src)[rf];
    int flatf = rf << 2;
    int n  = flatf >> Ksh;
    int k0 = flatf & ((1 << Ksh) - 1);
    ushort4 ov;
    ov.x = f2bfu(vv.x); ov.y = f2bfu(vv.y); ov.z = f2bfu(vv.z); ov.w = f2bfu(vv.w);
    *(ushort4*)(db + swidx(n, k0, 1 << (Ksh - 5))) = ov;
}

__global__ __launch_bounds__(256) void concat3_k(
    const float* __restrict__ a, const float* __restrict__ b,
    const float* __restrict__ c, float* __restrict__ o)
{
    int i = blockIdx.x * 256 + threadIdx.x;
    o[i] = (i < 1024) ? a[i] : ((i < 2048) ? b[i - 1024] : c[i - 2048]);
}

__global__ __launch_bounds__(256) void reorder_w_k(
    const float* __restrict__ src, unsigned short* __restrict__ dst, int OC, int IC)
{
    int idx = blockIdx.x * 256 + threadIdx.x;
    if (idx >= OC * IC * 3) return;
    int k  = idx % 3;
    int ic = (idx / 3) % IC;
    int oc = idx / (3 * IC);
    dst[(oc * 3 + k) * IC + ic] = f2bfu(src[idx]);
}

// meanpool split: 256-block partial pass (16 rows each, all 1024 d) then a
// 16-block reduce. Old single-pass version ran on only 16 CUs pulling 16 MB.
__global__ __launch_bounds__(256) void meanpool_part_k(
    const float* __restrict__ h, float* __restrict__ part)
{
    int g = blockIdx.x;                 // g = b*64 + rblk
    int b = g >> 6, rblk = g & 63;
    const float4* base = (const float4*)(h + ((long long)b << 20)
                                           + ((long long)(rblk * 16) << 10));
    float4 s = {0.f, 0.f, 0.f, 0.f};
#pragma unroll
    for (int i = 0; i < 16; i++) {
        float4 v = base[i * 256 + threadIdx.x];
        s.x += v.x; s.y += v.y; s.z += v.z; s.w += v.w;
    }
    ((float4*)part)[g * 256 + threadIdx.x] = s;
}

__global__ __launch_bounds__(256) void meanpool_red_k(
    const float* __restrict__ part, float* __restrict__ pooled)
{
    int idx = blockIdx.x * 256 + threadIdx.x;   // 4096: b = idx>>10, d = idx&1023
    int b = idx >> 10, d = idx & 1023;
    const float* p = part + ((long long)(b * 64) << 10) + d;
    float s = 0.f;
#pragma unroll 8
    for (int r = 0; r < 64; r++) s += p[r << 10];
    pooled[idx] = s * (1.0f / 1024.0f);
}

__global__ __launch_bounds__(256) void fc_k(
    const float* __restrict__ p, const float* __restrict__ w,
    const float* __restrict__ fb, float* __restrict__ out)
{
    int b = blockIdx.x, t = threadIdx.x;
    float s = 0.f;
    for (int i = t; i < 1024; i += 256) s += p[(b << 10) + i] * w[i];
#pragma unroll
    for (int o = 32; o; o >>= 1) s += __shfl_down(s, o);
    __shared__ float red[4];
    if ((t & 63) == 0) red[t >> 6] = s;
    __syncthreads();
    if (t == 0) out[b] = red[0] + red[1] + red[2] + red[3] + fb[0];
}

// ---------------------------------------------------------------------------
extern "C" void kernel_launch(void* const* d_in, const int* in_sizes, int n_in,
                              void* d_out, int out_size, void* d_ws, size_t ws_size,
                              hipStream_t stream)
{
    const float* x    = (const float*)d_in[0];
    const float* c1w  = (const float*)d_in[1];
    const float* c1b  = (const float*)d_in[2];
    const float* c2w  = (const float*)d_in[3];
    const float* c2b  = (const float*)d_in[4];
    const float* lnAw = (const float*)d_in[5];
    const float* lnAb = (const float*)d_in[6];
    const float* qw   = (const float*)d_in[7];
    const float* qbi  = (const float*)d_in[8];
    const float* kw   = (const float*)d_in[9];
    const float* kbi  = (const float*)d_in[10];
    const float* vw   = (const float*)d_in[11];
    const float* vbi  = (const float*)d_in[12];
    const float* ow   = (const float*)d_in[13];
    const float* obi  = (const float*)d_in[14];
    const float* lnBw = (const float*)d_in[15];
    const float* lnBb = (const float*)d_in[16];
    const float* f1w  = (const float*)d_in[17];
    const float* f1b  = (const float*)d_in[18];
    const float* f2w  = (const float*)d_in[19];
    const float* f2b  = (const float*)d_in[20];
    const float* fcw  = (const float*)d_in[21];
    const float* fcb  = (const float*)d_in[22];
    float* out = (float*)d_out;

    float* ws = (float*)d_ws;
    typedef __hip_bfloat16 bf;
    typedef unsigned short us;
    float* h    = ws;                          // 4,194,304 f
    us* hn_b    = (us*)(ws + 4194304);         // 4M us (swizzled activations)
    us* qkv_b   = (us*)(ws + 6291456);         // [4096][3072] us row-major
    us* ff_b    = qkv_b;                       // [4096][2048] swizzled overlay
    us* wq_b    = (us*)(ws + 12582912);        // swizzled: q,k,v,o,f1,f2
    us* wo_b    = (us*)(ws + 14155776);
    us* wf1_b   = (us*)(ws + 14680064);
    us* wf2_b   = (us*)(ws + 15728640);
    us* xb      = (us*)(ws + 16777216);
    us* h1b     = (us*)(ws + 16912896);
    us* w1t_b   = (us*)(ws + 17963520);
    us* w2t_b   = (us*)(ws + 18012672);
    float* pooled = ws + 18799104;             // 4,096 f
    us* Vt      = (us*)(ws + 18803200);        // [4][1024 d][1024 t] us
    float* bqkv = ws + 20900352;               // 3,072 f
    float* mp_part = ws + 20903424;            // 262,144 f (meanpool partials)

    convert_k<<<dim3(257), 256, 0, stream>>>(x, xb, 65792);
    reorder_w_k<<<dim3(384),  256, 0, stream>>>(c1w, w1t_b, 512, 64);
    reorder_w_k<<<dim3(6144), 256, 0, stream>>>(c2w, w2t_b, 1024, 512);

    // conv1: M=4104, N=512, K=192 (LDS-staged kernel, row-remapped A)
    gemm_mfma_k<<<dim3(8, 33), 256, 0, stream>>>(
        (const bf*)xb, 1026, 1028LL * 64, 64, (const bf*)w1t_b,
        c1b, nullptr, nullptr, (bf*)h1b, 4104, 512, 192, 512, 0);
    // conv2: M=4096, N=1024, K=1536
    gemm_mfma_k<<<dim3(16, 32), 256, 0, stream>>>(
        (const bf*)h1b, 1024, 1026LL * 512, 512, (const bf*)w2t_b,
        c2b, nullptr, h, nullptr, 4096, 1024, 1536, 1024, 0);
    add_pos_k<<<dim3(16384), 256, 0, stream>>>(h);

    for (int l = 0; l < 4; l++) {
        long long wo  = (long long)l * 1048576;
        long long wo2 = (long long)l * 2097152;
        convert_layer_sw_k<<<dim3(8192), 256, 0, stream>>>(
            qw + wo, kw + wo, vw + wo, ow + wo, f1w + wo2, f2w + wo2, wq_b);
        concat3_k<<<dim3(12), 256, 0, stream>>>(qbi + l * 1024, kbi + l * 1024,
                                                vbi + l * 1024, bqkv);

        layernorm_k<<<dim3(4096), 256, 0, stream>>>(h, lnAw + l * 1024, lnAb + l * 1024, hn_b);
        // fused QKV: N=3072; Q,K swizzled to qkv_b; V transposed to Vt
        gemm_sw_k<<<dim3(48, 64), 64, 0, stream>>>(
            hn_b, wq_b, bqkv, nullptr, nullptr, qkv_b, nullptr, Vt, 2048,
            4096, 3072, 1024, 3072, 0);
        attn_mfma_k<<<dim3(8, 64), 256, 0, stream>>>(qkv_b, Vt, hn_b);
        // O-proj: out fp32 h += res
        gemm_sw_k<<<dim3(16, 64), 64, 0, stream>>>(
            hn_b, wo_b, obi + l * 1024, h, h, nullptr, nullptr, nullptr, 0,
            4096, 1024, 1024, 1024, 0);
        layernorm_k<<<dim3(4096), 256, 0, stream>>>(h, lnBw + l * 1024, lnBb + l * 1024, hn_b);
        // FF1: out swizzled bf16 (+relu)
        gemm_sw_k<<<dim3(32, 64), 64, 0, stream>>>(
            hn_b, wf1_b, f1b + l * 2048, nullptr, nullptr, nullptr, ff_b, nullptr, 0,
            4096, 2048, 1024, 2048, 1);
        // FF2: out fp32 h += res
        gemm_sw_k<<<dim3(16, 64), 64, 0, stream>>>(
            ff_b, wf2_b, f2b + l * 1024, h, h, nullptr, nullptr, nullptr, 0,
            4096, 1024, 2048, 1024, 0);
    }

    meanpool_part_k<<<dim3(256), 256, 0, stream>>>(h, mp_part);
    meanpool_red_k<<<dim3(16), 256, 0, stream>>>(mp_part, pooled);
    fc_k<<<dim3(4), 256, 0, stream>>>(pooled, fcw, fcb, out);
}

// Round 5
// 1121.656 us; speedup vs baseline: 1.1405x; 1.0193x over previous
//
#include <hip/hip_runtime.h>
#include <hip/hip_bf16.h>
#include <math.h>

// ---------------------------------------------------------------------------
// helpers
// ---------------------------------------------------------------------------
typedef __bf16 v8bf __attribute__((ext_vector_type(8)));
typedef float  v4f  __attribute__((ext_vector_type(4)));
typedef unsigned short v8us __attribute__((ext_vector_type(8)));

__device__ __forceinline__ unsigned short f2bfu(float f) {
    unsigned u = __builtin_bit_cast(unsigned, f);
    unsigned r = (u + 0x7fffu + ((u >> 16) & 1u)) >> 16;
    return (unsigned short)r;
}
__device__ __forceinline__ float bf2f(unsigned short u) {
    unsigned x = ((unsigned)u) << 16;
    return __builtin_bit_cast(float, x);
}

// fragment-swizzled element address: matrix [rows][K cols] stored so that a
// wave's 16x32 MFMA fragment is contiguous: sw(r,k) =
//   tile(r>>4, k>>5) * 512 + lane((k>>3)&3, r&15) * 8 + (k&7)
__device__ __forceinline__ long long swidx(int r, int k, int kt /*=K>>5*/) {
    return ((long long)((r >> 4) * kt + (k >> 5)) << 9)
         + (((k >> 3) & 3) << 7) + ((r & 15) << 3) + (k & 7);
}

#define GLDS16(g, s)                                                        \
    __builtin_amdgcn_global_load_lds(                                       \
        (const __attribute__((address_space(1))) void*)(g),                 \
        (__attribute__((address_space(3))) void*)(s), 16, 0, 0)

// ---------------------------------------------------------------------------
// SWIZZLED register-direct bf16 MFMA GEMM (no LDS, no barriers).
// A (M x K) and B (N x K) in fragment-swizzled layout (see swidx).
// ONE WAVE PER BLOCK (64 threads), wave tile 64x64.
// K-loop: depth-4 register ring, prefetch distance 3 chunks, with
// __builtin_amdgcn_sched_barrier(0) pinning.
// R4 post-mortem: VGPR_Count=96 proved the LLVM scheduler SANK the ring's
// prefetch loads to just before their consuming MFMAs (live-range
// minimization), de-pipelining every source-level ring (R1 VGPR=80, R3
// VGPR=108, R4 VGPR=96 — all latency-serialized at ~400cy/chunk, MfmaUtil
// pinned ~18%). sched_barrier(0) after each LOAD_CHUNK forbids sinking:
// ring-r loads retire >=3 phases before MFMA_CHUNK(r), and the compiler's
// dependency-tracked waitcnt becomes a counted vmcnt(~24) instead of a
// per-chunk drain. Verification signal: VGPR_Count must jump to ~200+.
// Outputs: Cf (fp32,+res row-major) | Cb (bf16 row-major) | Csw (bf16
// swizzled for the next GEMM, K_consumer = N) ; cols >= ctcol0 (Ct!=null)
// go transposed to Ct (attention V^T). M,N multiples of 64, kt=K/32
// a multiple of 4 and >= 8 (kt = 32 or 64 here).
// ---------------------------------------------------------------------------
#define LOAD_CHUNK(R, C) do {                                               \
    const long long o_ = (long long)(C) << 9;                               \
    _Pragma("unroll")                                                       \
    for (int i_ = 0; i_ < 4; i_++) Ab[R][i_] = *(const v8bf*)(pa[i_] + o_); \
    _Pragma("unroll")                                                       \
    for (int j_ = 0; j_ < 4; j_++) Bb[R][j_] = *(const v8bf*)(pb[j_] + o_); \
} while (0)

#define MFMA_CHUNK(R) do {                                                  \
    _Pragma("unroll")                                                       \
    for (int i_ = 0; i_ < 4; i_++)                                          \
    _Pragma("unroll")                                                       \
    for (int j_ = 0; j_ < 4; j_++)                                          \
        acc[i_][j_] = __builtin_amdgcn_mfma_f32_16x16x32_bf16(              \
            Ab[R][i_], Bb[R][j_], acc[i_][j_], 0, 0, 0);                    \
} while (0)

#define SBAR() __builtin_amdgcn_sched_barrier(0)

__global__ __launch_bounds__(64, 2) void gemm_sw_k(
    const unsigned short* __restrict__ Asw,
    const unsigned short* __restrict__ Bsw,
    const float* __restrict__ bias,
    const float* __restrict__ res,
    float* __restrict__ Cf,
    unsigned short* __restrict__ Cb,
    unsigned short* __restrict__ Csw,
    unsigned short* __restrict__ Ct, int ctcol0,
    int M, int N, int K, int ldC, int relu)
{
    const int l = threadIdx.x;

    int bx = blockIdx.x, by = blockIdx.y;
    {
        int nbx = gridDim.x;
        int nb  = nbx * gridDim.y;
        if ((nb & 7) == 0) {
            int bid = by * nbx + bx;
            int nid = (bid & 7) * (nb >> 3) + (bid >> 3);
            by = nid / nbx;
            bx = nid - by * nbx;
        }
    }
    const int m0 = by * 64;
    const int n0 = bx * 64;
    const int r16 = l & 15;
    const int qb  = l >> 4;
    const int kt = K >> 5;

    // fragment base pointers: contiguous 16B per lane
    const unsigned short* pa[4];
#pragma unroll
    for (int i = 0; i < 4; i++)
        pa[i] = Asw + ((long long)(((m0 >> 4) + i) * kt) << 9) + l * 8;
    const unsigned short* pb[4];
#pragma unroll
    for (int j = 0; j < 4; j++)
        pb[j] = Bsw + ((long long)(((n0 >> 4) + j) * kt) << 9) + l * 8;

    v4f acc[4][4];
#pragma unroll
    for (int i = 0; i < 4; i++)
#pragma unroll
        for (int j = 0; j < 4; j++) acc[i][j] = (v4f){0.f, 0.f, 0.f, 0.f};

    v8bf Ab[4][4], Bb[4][4];

    // prologue: chunks 0,1,2 -> rings 0,1,2
    LOAD_CHUNK(0, 0);
    LOAD_CHUNK(1, 1);
    LOAD_CHUNK(2, 2);

    // steady state: straight-line, literal ring indices; sched_barrier(0)
    // after each load cluster forbids the scheduler from sinking prefetches
    // into later phases (R1-R4 failure mode).
    int s = 0;
    for (; s < kt - 4; s += 4) {
        LOAD_CHUNK(3, s + 3); SBAR(); MFMA_CHUNK(0);
        LOAD_CHUNK(0, s + 4); SBAR(); MFMA_CHUNK(1);
        LOAD_CHUNK(1, s + 5); SBAR(); MFMA_CHUNK(2);
        LOAD_CHUNK(2, s + 6); SBAR(); MFMA_CHUNK(3);
    }
    // epilogue: s == kt-4; rings hold kt-4,kt-3,kt-2; load last chunk.
    LOAD_CHUNK(3, kt - 1); SBAR();
    MFMA_CHUNK(0); MFMA_CHUNK(1); MFMA_CHUNK(2); MFMA_CHUNK(3);

    float bv[4];
#pragma unroll
    for (int j = 0; j < 4; j++) bv[j] = bias[n0 + 16 * j + r16];
    const int colbase = n0 + r16;
    const int nt = N >> 5;
#pragma unroll
    for (int i = 0; i < 4; i++) {
        int rowb = m0 + 16 * i + qb * 4;
#pragma unroll
        for (int j = 0; j < 4; j++) {
            int col = colbase + 16 * j;
            float v[4];
#pragma unroll
            for (int r = 0; r < 4; r++) v[r] = acc[i][j][r] + bv[j];
            if (Ct && col >= ctcol0) {
                ushort4 o;
                o.x = f2bfu(v[0]); o.y = f2bfu(v[1]);
                o.z = f2bfu(v[2]); o.w = f2bfu(v[3]);
                *(ushort4*)(Ct + ((long long)(rowb >> 10) << 20)
                            + (long long)(col - ctcol0) * 1024 + (rowb & 1023)) = o;
            } else if (Csw) {
#pragma unroll
                for (int r = 0; r < 4; r++) {
                    int row = rowb + r;
                    float vv = v[r];
                    if (relu) vv = fmaxf(vv, 0.f);
                    Csw[swidx(row, col, nt)] = f2bfu(vv);
                }
            } else {
#pragma unroll
                for (int r = 0; r < 4; r++) {
                    int row = rowb + r;
                    long long off = (long long)row * ldC + col;
                    float vv = v[r];
                    if (res)  vv += res[off];
                    if (relu) vv = fmaxf(vv, 0.f);
                    if (Cf) Cf[off] = vv;
                    if (Cb) ((unsigned short*)Cb)[off] = f2bfu(vv);
                }
            }
        }
    }
}

// ---------------------------------------------------------------------------
// LDS-staged GEMM (R5) — kept for the conv frontend (row-remapped A).
// ---------------------------------------------------------------------------
__global__ __launch_bounds__(256) void gemm_mfma_k(
    const __hip_bfloat16* __restrict__ A, int rpbA, long long bstrideA, int ldA,
    const __hip_bfloat16* __restrict__ B,
    const float* __restrict__ bias,
    const float* __restrict__ res,
    float* __restrict__ Cf,
    __hip_bfloat16* __restrict__ Cb,
    int M, int N, int K, int ldC, int relu)
{
    __shared__ __align__(16) __hip_bfloat16 As[2][8][64][8];
    __shared__ __align__(16) __hip_bfloat16 Bs[2][4][64][8];
    const int t  = threadIdx.x;
    const int w  = t >> 6;
    const int l  = t & 63;
    const int m0 = blockIdx.y * 128;
    const int n0 = blockIdx.x * 64;
    const int r16 = l & 15;
    const int qb  = l >> 4;
    const int wm = w >> 1, wn = w & 1;

    const __hip_bfloat16* gA[2];
#pragma unroll
    for (int tt = 0; tt < 2; tt++) {
        int arow = m0 + 16 * (2 * w + tt) + r16;
        gA[tt] = A + (long long)(arow / rpbA) * bstrideA
                   + (long long)(arow % rpbA) * ldA + qb * 8;
    }
    const __hip_bfloat16* gB = B + (long long)(n0 + 16 * w + r16) * K + qb * 8;

    v4f acc[4][2];
#pragma unroll
    for (int i = 0; i < 4; i++)
#pragma unroll
        for (int j = 0; j < 2; j++) acc[i][j] = (v4f){0.f, 0.f, 0.f, 0.f};

    GLDS16(gA[0], &As[0][2 * w + 0][0][0]);
    GLDS16(gA[1], &As[0][2 * w + 1][0][0]);
    GLDS16(gB,    &Bs[0][w][0][0]);
    __syncthreads();

    int cur = 0;
    for (int k0 = 32; k0 < K; k0 += 32) {
        v8bf af[4], bfr[2];
#pragma unroll
        for (int i = 0; i < 4; i++) af[i]  = *(const v8bf*)(&As[cur][4 * wm + i][l][0]);
#pragma unroll
        for (int j = 0; j < 2; j++) bfr[j] = *(const v8bf*)(&Bs[cur][2 * wn + j][l][0]);
        GLDS16(gA[0] + k0, &As[cur ^ 1][2 * w + 0][0][0]);
        GLDS16(gA[1] + k0, &As[cur ^ 1][2 * w + 1][0][0]);
        GLDS16(gB + k0,    &Bs[cur ^ 1][w][0][0]);
#pragma unroll
        for (int i = 0; i < 4; i++)
#pragma unroll
            for (int j = 0; j < 2; j++)
                acc[i][j] = __builtin_amdgcn_mfma_f32_16x16x32_bf16(
                    af[i], bfr[j], acc[i][j], 0, 0, 0);
        __syncthreads();
        cur ^= 1;
    }
    {
        v8bf af[4], bfr[2];
#pragma unroll
        for (int i = 0; i < 4; i++) af[i]  = *(const v8bf*)(&As[cur][4 * wm + i][l][0]);
#pragma unroll
        for (int j = 0; j < 2; j++) bfr[j] = *(const v8bf*)(&Bs[cur][2 * wn + j][l][0]);
#pragma unroll
        for (int i = 0; i < 4; i++)
#pragma unroll
            for (int j = 0; j < 2; j++)
                acc[i][j] = __builtin_amdgcn_mfma_f32_16x16x32_bf16(
                    af[i], bfr[j], acc[i][j], 0, 0, 0);
    }

    float bv[2];
#pragma unroll
    for (int j = 0; j < 2; j++) bv[j] = bias[n0 + 32 * wn + 16 * j + r16];
    const int colbase = n0 + 32 * wn + r16;
#pragma unroll
    for (int i = 0; i < 4; i++) {
        int rowb = m0 + 64 * wm + 16 * i + qb * 4;
#pragma unroll
        for (int j = 0; j < 2; j++) {
            int col = colbase + 16 * j;
#pragma unroll
            for (int r = 0; r < 4; r++) {
                int row = rowb + r;
                if (row >= M) continue;
                long long off = (long long)row * ldC + col;
                float vv = acc[i][j][r] + bv[j];
                if (res)  vv += res[off];
                if (relu) vv = fmaxf(vv, 0.f);
                if (Cf) Cf[off] = vv;
                if (Cb) ((unsigned short*)Cb)[off] = f2bfu(vv);
            }
        }
    }
}

// ---------------------------------------------------------------------------
// MFMA softsign attention. Output written in SWIZZLED layout (K=1024 -> 32).
// ---------------------------------------------------------------------------
__global__ __launch_bounds__(256) void attn_mfma_k(
    const unsigned short* __restrict__ QKV,
    const unsigned short* __restrict__ Vt,
    unsigned short* __restrict__ Osw)
{
    __shared__ __align__(16) unsigned short lds[25600];
    const int t = threadIdx.x, w = t >> 6, l = t & 63;
    const int bh = blockIdx.y, b = bh >> 4, h = bh & 15;
    const int s0 = blockIdx.x << 7;
    const int r16 = l & 15, q4 = l >> 4;
    const long long qrow0 = (long long)(b << 10) + s0;
    const int hoff = h << 6;

#pragma unroll
    for (int mi = 0; mi < 2; mi++)
#pragma unroll
        for (int kk = 0; kk < 2; kk++) {
            const unsigned short* g = QKV + (qrow0 + 32 * w + 16 * mi + r16) * 3072
                                      + hoff + 32 * kk + q4 * 8;
            GLDS16(g, &lds[(w * 4 + mi * 2 + kk) * 512]);
        }
    __syncthreads();
    v8bf qf[2][2];
#pragma unroll
    for (int mi = 0; mi < 2; mi++)
#pragma unroll
        for (int kk = 0; kk < 2; kk++)
            qf[mi][kk] = *(const v8bf*)&lds[(w * 4 + mi * 2 + kk) * 512 + l * 8];

    v4f oacc[2][4];
#pragma unroll
    for (int i = 0; i < 2; i++)
#pragma unroll
        for (int j = 0; j < 4; j++) oacc[i][j] = (v4f){0.f, 0.f, 0.f, 0.f};

    for (int t0 = 0; t0 < 1024; t0 += 64) {
#pragma unroll
        for (int rr = 0; rr < 2; rr++) {
            int r = 2 * w + rr, kk = r >> 2, j = r & 3;
            const unsigned short* gk = QKV
                + ((long long)(b << 10) + t0 + 16 * j + r16) * 3072
                + 1024 + hoff + 32 * kk + q4 * 8;
            GLDS16(gk, &lds[8192 + r * 512]);
            const unsigned short* gv = Vt + ((long long)b << 20)
                + (long long)(hoff + 16 * j + r16) * 1024 + t0 + 32 * kk + q4 * 8;
            GLDS16(gv, &lds[12288 + r * 512]);
        }
        __syncthreads();

        v8bf kf[2][4];
#pragma unroll
        for (int kk = 0; kk < 2; kk++)
#pragma unroll
            for (int j = 0; j < 4; j++)
                kf[kk][j] = *(const v8bf*)&lds[8192 + (kk * 4 + j) * 512 + l * 8];
        v4f sc[2][4];
#pragma unroll
        for (int i = 0; i < 2; i++)
#pragma unroll
            for (int j = 0; j < 4; j++) sc[i][j] = (v4f){0.f, 0.f, 0.f, 0.f};
#pragma unroll
        for (int kk = 0; kk < 2; kk++)
#pragma unroll
            for (int mi = 0; mi < 2; mi++)
#pragma unroll
                for (int j = 0; j < 4; j++)
                    sc[mi][j] = __builtin_amdgcn_mfma_f32_16x16x32_bf16(
                        qf[mi][kk], kf[kk][j], sc[mi][j], 0, 0, 0);

#pragma unroll
        for (int mi = 0; mi < 2; mi++)
#pragma unroll
            for (int j = 0; j < 4; j++)
#pragma unroll
                for (int r = 0; r < 4; r++) {
                    float v = sc[mi][j][r] * 0.125f;
                    float p = v * __builtin_amdgcn_rcpf(1.0f + fabsf(v));
                    lds[16384 + (32 * w + 16 * mi + q4 * 4 + r) * 72 + 16 * j + r16] = f2bfu(p);
                }

        v8bf pf[2][2], vf[2][4];
#pragma unroll
        for (int mi = 0; mi < 2; mi++)
#pragma unroll
            for (int kk = 0; kk < 2; kk++)
                pf[mi][kk] = *(const v8bf*)&lds[16384 + (32 * w + 16 * mi + r16) * 72
                                                + 32 * kk + q4 * 8];
#pragma unroll
        for (int kk = 0; kk < 2; kk++)
#pragma unroll
            for (int j = 0; j < 4; j++)
                vf[kk][j] = *(const v8bf*)&lds[12288 + (kk * 4 + j) * 512 + l * 8];
#pragma unroll
        for (int kk = 0; kk < 2; kk++)
#pragma unroll
            for (int mi = 0; mi < 2; mi++)
#pragma unroll
                for (int j = 0; j < 4; j++)
                    oacc[mi][j] = __builtin_amdgcn_mfma_f32_16x16x32_bf16(
                        pf[mi][kk], vf[kk][j], oacc[mi][j], 0, 0, 0);
        __syncthreads();
    }

#pragma unroll
    for (int mi = 0; mi < 2; mi++)
#pragma unroll
        for (int j = 0; j < 4; j++)
#pragma unroll
            for (int r = 0; r < 4; r++)
                lds[(32 * w + 16 * mi + q4 * 4 + r) * 72 + 16 * j + r16] =
                    f2bfu(oacc[mi][j][r]);
    __syncthreads();
    {
        int row = t >> 1, ch = (t & 1) << 5;
        int grow = (int)qrow0 + row;
#pragma unroll
        for (int i = 0; i < 4; i++) {
            int c0 = hoff + ch + 8 * i;
            v8us vv = *(const v8us*)&lds[row * 72 + ch + 8 * i];
            *(v8us*)(Osw + swidx(grow, c0, 32)) = vv;
        }
    }
}

// ---------------------------------------------------------------------------
// LayerNorm (torch-style), output bf16 in SWIZZLED layout (K=1024).
// ---------------------------------------------------------------------------
__global__ __launch_bounds__(256) void layernorm_k(
    const float* __restrict__ x, const float* __restrict__ w,
    const float* __restrict__ b, unsigned short* __restrict__ ysw)
{
    int row = blockIdx.x;
    int t = threadIdx.x;
    float4 v = ((const float4*)(x + ((long long)row << 10)))[t];
    float s = v.x + v.y + v.z + v.w;
#pragma unroll
    for (int o = 32; o; o >>= 1) s += __shfl_down(s, o);
    __shared__ float red[4];
    __shared__ float red2[4];
    int wid = t >> 6, lane = t & 63;
    if (lane == 0) red[wid] = s;
    __syncthreads();
    float mean = (red[0] + red[1] + red[2] + red[3]) * (1.0f / 1024.0f);
    float dx = v.x - mean, dy = v.y - mean, dz = v.z - mean, dw = v.w - mean;
    float sq = dx * dx + dy * dy + dz * dz + dw * dw;
#pragma unroll
    for (int o = 32; o; o >>= 1) sq += __shfl_down(sq, o);
    if (lane == 0) red2[wid] = sq;
    __syncthreads();
    float var = (red2[0] + red2[1] + red2[2] + red2[3]) * (1.0f / 1023.0f);
    float inv = 1.0f / (sqrtf(var) + 1e-6f);
    float4 W  = ((const float4*)w)[t];
    float4 Bv = ((const float4*)b)[t];
    ushort4 o;
    o.x = f2bfu(W.x * (dx * inv) + Bv.x);
    o.y = f2bfu(W.y * (dy * inv) + Bv.y);
    o.z = f2bfu(W.z * (dz * inv) + Bv.z);
    o.w = f2bfu(W.w * (dw * inv) + Bv.w);
    int c0 = t << 2;
    *(ushort4*)(ysw + swidx(row, c0, 32)) = o;
}

// ---------------------------------------------------------------------------
__global__ __launch_bounds__(256) void add_pos_k(float* __restrict__ h)
{
    int idx = blockIdx.x * 256 + threadIdx.x;
    int d = idx & 1023;
    int s = (idx >> 10) & 1023;
    int e = d & ~1;
    float div = expf(-9.210340371976184f * (float)e * (1.0f / 1024.0f));
    float arg = (float)s * div;
    float pe = (d & 1) ? cosf(arg) : sinf(arg);
    h[idx] += pe;
}

__global__ __launch_bounds__(256) void convert_k(
    const float* __restrict__ src, unsigned short* __restrict__ dst, int n4)
{
    int i = blockIdx.x * 256 + threadIdx.x;
    if (i >= n4) return;
    float4 v = ((const float4*)src)[i];
    ushort4 o;
    o.x = f2bfu(v.x); o.y = f2bfu(v.y); o.z = f2bfu(v.z); o.w = f2bfu(v.w);
    ((ushort4*)dst)[i] = o;
}

// Layer weights fp32 row-major -> bf16 SWIZZLED, all 6 matrices, one launch.
// dst layout (us): q,k,v,o (1M each), f1 (2M), f2 (2M) — contiguous.
__global__ __launch_bounds__(256) void convert_layer_sw_k(
    const float* __restrict__ q, const float* __restrict__ k,
    const float* __restrict__ v, const float* __restrict__ o,
    const float* __restrict__ f1, const float* __restrict__ f2,
    unsigned short* __restrict__ dst)
{
    int idx = blockIdx.x * 256 + threadIdx.x;   // float4 index, [0, 2M)
    const float* src;
    unsigned short* db;
    int Ksh, rf;
    if (idx < 0x100000) {
        int region = idx >> 18;
        rf = idx & 0x3FFFF;
        src = (region == 0) ? q : (region == 1) ? k : (region == 2) ? v : o;
        db = dst + ((long long)region << 20);
        Ksh = 10;
    } else if (idx < 0x180000) {
        rf = idx - 0x100000; src = f1; db = dst + (4LL << 20); Ksh = 10;
    } else {
        rf = idx - 0x180000; src = f2; db = dst + (6LL << 20); Ksh = 11;
    }
    float4 vv = ((const float4*)src)[rf];
    int flatf = rf << 2;
    int n  = flatf >> Ksh;
    int k0 = flatf & ((1 << Ksh) - 1);
    ushort4 ov;
    ov.x = f2bfu(vv.x); ov.y = f2bfu(vv.y); ov.z = f2bfu(vv.z); ov.w = f2bfu(vv.w);
    *(ushort4*)(db + swidx(n, k0, 1 << (Ksh - 5))) = ov;
}

__global__ __launch_bounds__(256) void concat3_k(
    const float* __restrict__ a, const float* __restrict__ b,
    const float* __restrict__ c, float* __restrict__ o)
{
    int i = blockIdx.x * 256 + threadIdx.x;
    o[i] = (i < 1024) ? a[i] : ((i < 2048) ? b[i - 1024] : c[i - 2048]);
}

__global__ __launch_bounds__(256) void reorder_w_k(
    const float* __restrict__ src, unsigned short* __restrict__ dst, int OC, int IC)
{
    int idx = blockIdx.x * 256 + threadIdx.x;
    if (idx >= OC * IC * 3) return;
    int k  = idx % 3;
    int ic = (idx / 3) % IC;
    int oc = idx / (3 * IC);
    dst[(oc * 3 + k) * IC + ic] = f2bfu(src[idx]);
}

// meanpool split: 256-block partial pass (16 rows each, all 1024 d) then a
// 16-block reduce. Old single-pass version ran on only 16 CUs pulling 16 MB.
__global__ __launch_bounds__(256) void meanpool_part_k(
    const float* __restrict__ h, float* __restrict__ part)
{
    int g = blockIdx.x;                 // g = b*64 + rblk
    int b = g >> 6, rblk = g & 63;
    const float4* base = (const float4*)(h + ((long long)b << 20)
                                           + ((long long)(rblk * 16) << 10));
    float4 s = {0.f, 0.f, 0.f, 0.f};
#pragma unroll
    for (int i = 0; i < 16; i++) {
        float4 v = base[i * 256 + threadIdx.x];
        s.x += v.x; s.y += v.y; s.z += v.z; s.w += v.w;
    }
    ((float4*)part)[g * 256 + threadIdx.x] = s;
}

__global__ __launch_bounds__(256) void meanpool_red_k(
    const float* __restrict__ part, float* __restrict__ pooled)
{
    int idx = blockIdx.x * 256 + threadIdx.x;   // 4096: b = idx>>10, d = idx&1023
    int b = idx >> 10, d = idx & 1023;
    const float* p = part + ((long long)(b * 64) << 10) + d;
    float s = 0.f;
#pragma unroll 8
    for (int r = 0; r < 64; r++) s += p[r << 10];
    pooled[idx] = s * (1.0f / 1024.0f);
}

__global__ __launch_bounds__(256) void fc_k(
    const float* __restrict__ p, const float* __restrict__ w,
    const float* __restrict__ fb, float* __restrict__ out)
{
    int b = blockIdx.x, t = threadIdx.x;
    float s = 0.f;
    for (int i = t; i < 1024; i += 256) s += p[(b << 10) + i] * w[i];
#pragma unroll
    for (int o = 32; o; o >>= 1) s += __shfl_down(s, o);
    __shared__ float red[4];
    if ((t & 63) == 0) red[t >> 6] = s;
    __syncthreads();
    if (t == 0) out[b] = red[0] + red[1] + red[2] + red[3] + fb[0];
}

// ---------------------------------------------------------------------------
extern "C" void kernel_launch(void* const* d_in, const int* in_sizes, int n_in,
                              void* d_out, int out_size, void* d_ws, size_t ws_size,
                              hipStream_t stream)
{
    const float* x    = (const float*)d_in[0];
    const float* c1w  = (const float*)d_in[1];
    const float* c1b  = (const float*)d_in[2];
    const float* c2w  = (const float*)d_in[3];
    const float* c2b  = (const float*)d_in[4];
    const float* lnAw = (const float*)d_in[5];
    const float* lnAb = (const float*)d_in[6];
    const float* qw   = (const float*)d_in[7];
    const float* qbi  = (const float*)d_in[8];
    const float* kw   = (const float*)d_in[9];
    const float* kbi  = (const float*)d_in[10];
    const float* vw   = (const float*)d_in[11];
    const float* vbi  = (const float*)d_in[12];
    const float* ow   = (const float*)d_in[13];
    const float* obi  = (const float*)d_in[14];
    const float* lnBw = (const float*)d_in[15];
    const float* lnBb = (const float*)d_in[16];
    const float* f1w  = (const float*)d_in[17];
    const float* f1b  = (const float*)d_in[18];
    const float* f2w  = (const float*)d_in[19];
    const float* f2b  = (const float*)d_in[20];
    const float* fcw  = (const float*)d_in[21];
    const float* fcb  = (const float*)d_in[22];
    float* out = (float*)d_out;

    float* ws = (float*)d_ws;
    typedef __hip_bfloat16 bf;
    typedef unsigned short us;
    float* h    = ws;                          // 4,194,304 f
    us* hn_b    = (us*)(ws + 4194304);         // 4M us (swizzled activations)
    us* qkv_b   = (us*)(ws + 6291456);         // [4096][3072] us row-major
    us* ff_b    = qkv_b;                       // [4096][2048] swizzled overlay
    us* wq_b    = (us*)(ws + 12582912);        // swizzled: q,k,v,o,f1,f2
    us* wo_b    = (us*)(ws + 14155776);
    us* wf1_b   = (us*)(ws + 14680064);
    us* wf2_b   = (us*)(ws + 15728640);
    us* xb      = (us*)(ws + 16777216);
    us* h1b     = (us*)(ws + 16912896);
    us* w1t_b   = (us*)(ws + 17963520);
    us* w2t_b   = (us*)(ws + 18012672);
    float* pooled = ws + 18799104;             // 4,096 f
    us* Vt      = (us*)(ws + 18803200);        // [4][1024 d][1024 t] us
    float* bqkv = ws + 20900352;               // 3,072 f
    float* mp_part = ws + 20903424;            // 262,144 f (meanpool partials)

    convert_k<<<dim3(257), 256, 0, stream>>>(x, xb, 65792);
    reorder_w_k<<<dim3(384),  256, 0, stream>>>(c1w, w1t_b, 512, 64);
    reorder_w_k<<<dim3(6144), 256, 0, stream>>>(c2w, w2t_b, 1024, 512);

    // conv1: M=4104, N=512, K=192 (LDS-staged kernel, row-remapped A)
    gemm_mfma_k<<<dim3(8, 33), 256, 0, stream>>>(
        (const bf*)xb, 1026, 1028LL * 64, 64, (const bf*)w1t_b,
        c1b, nullptr, nullptr, (bf*)h1b, 4104, 512, 192, 512, 0);
    // conv2: M=4096, N=1024, K=1536
    gemm_mfma_k<<<dim3(16, 32), 256, 0, stream>>>(
        (const bf*)h1b, 1024, 1026LL * 512, 512, (const bf*)w2t_b,
        c2b, nullptr, h, nullptr, 4096, 1024, 1536, 1024, 0);
    add_pos_k<<<dim3(16384), 256, 0, stream>>>(h);

    for (int l = 0; l < 4; l++) {
        long long wo  = (long long)l * 1048576;
        long long wo2 = (long long)l * 2097152;
        convert_layer_sw_k<<<dim3(8192), 256, 0, stream>>>(
            qw + wo, kw + wo, vw + wo, ow + wo, f1w + wo2, f2w + wo2, wq_b);
        concat3_k<<<dim3(12), 256, 0, stream>>>(qbi + l * 1024, kbi + l * 1024,
                                                vbi + l * 1024, bqkv);

        layernorm_k<<<dim3(4096), 256, 0, stream>>>(h, lnAw + l * 1024, lnAb + l * 1024, hn_b);
        // fused QKV: N=3072; Q,K swizzled to qkv_b; V transposed to Vt
        gemm_sw_k<<<dim3(48, 64), 64, 0, stream>>>(
            hn_b, wq_b, bqkv, nullptr, nullptr, qkv_b, nullptr, Vt, 2048,
            4096, 3072, 1024, 3072, 0);
        attn_mfma_k<<<dim3(8, 64), 256, 0, stream>>>(qkv_b, Vt, hn_b);
        // O-proj: out fp32 h += res
        gemm_sw_k<<<dim3(16, 64), 64, 0, stream>>>(
            hn_b, wo_b, obi + l * 1024, h, h, nullptr, nullptr, nullptr, 0,
            4096, 1024, 1024, 1024, 0);
        layernorm_k<<<dim3(4096), 256, 0, stream>>>(h, lnBw + l * 1024, lnBb + l * 1024, hn_b);
        // FF1: out swizzled bf16 (+relu)
        gemm_sw_k<<<dim3(32, 64), 64, 0, stream>>>(
            hn_b, wf1_b, f1b + l * 2048, nullptr, nullptr, nullptr, ff_b, nullptr, 0,
            4096, 2048, 1024, 2048, 1);
        // FF2: out fp32 h += res
        gemm_sw_k<<<dim3(16, 64), 64, 0, stream>>>(
            ff_b, wf2_b, f2b + l * 1024, h, h, nullptr, nullptr, nullptr, 0,
            4096, 1024, 2048, 1024, 0);
    }

    meanpool_part_k<<<dim3(256), 256, 0, stream>>>(h, mp_part);
    meanpool_red_k<<<dim3(16), 256, 0, stream>>>(mp_part, pooled);
    fc_k<<<dim3(4), 256, 0, stream>>>(pooled, fcw, fcb, out);
}

// Round 6
// 1108.257 us; speedup vs baseline: 1.1543x; 1.0121x over previous
//
#include <hip/hip_runtime.h>
#include <hip/hip_bf16.h>
#include <math.h>

// ---------------------------------------------------------------------------
// helpers
// ---------------------------------------------------------------------------
typedef __bf16 v8bf __attribute__((ext_vector_type(8)));
typedef float  v4f  __attribute__((ext_vector_type(4)));
typedef unsigned short v8us __attribute__((ext_vector_type(8)));

__device__ __forceinline__ unsigned short f2bfu(float f) {
    unsigned u = __builtin_bit_cast(unsigned, f);
    unsigned r = (u + 0x7fffu + ((u >> 16) & 1u)) >> 16;
    return (unsigned short)r;
}
__device__ __forceinline__ float bf2f(unsigned short u) {
    unsigned x = ((unsigned)u) << 16;
    return __builtin_bit_cast(float, x);
}

// fragment-swizzled element address: matrix [rows][K cols] stored so that a
// wave's 16x32 MFMA fragment is contiguous: sw(r,k) =
//   tile(r>>4, k>>5) * 512 + lane((k>>3)&3, r&15) * 8 + (k&7)
__device__ __forceinline__ long long swidx(int r, int k, int kt /*=K>>5*/) {
    return ((long long)((r >> 4) * kt + (k >> 5)) << 9)
         + (((k >> 3) & 3) << 7) + ((r & 15) << 3) + (k & 7);
}

#define GLDS16(g, s)                                                        \
    __builtin_amdgcn_global_load_lds(                                       \
        (const __attribute__((address_space(1))) void*)(g),                 \
        (__attribute__((address_space(3))) void*)(s), 16, 0, 0)

// ---------------------------------------------------------------------------
// SWIZZLED register-direct bf16 MFMA GEMM — INLINE-ASM PIPELINED K-LOOP.
// A (M x K) and B (N x K) in fragment-swizzled layout (see swidx).
// ONE WAVE PER BLOCK (64 threads), wave tile 64x64.
//
// R1-R5 post-mortem: every source-level register ring was de-pipelined by
// the compiler (VGPR 80/96/108 vs the ~192 a live depth-4 ring needs;
// MfmaUtil pinned 16-19%; one full memory round-trip per 8KB chunk).
// sched_barrier(0) on plain loads did NOT pin (R5: VGPR still 108, QKV
// 50->62.7 regression). This version makes the pipeline opaque:
//  - loads are asm volatile global_load_dwordx4 ("=v" outputs -> the 128
//    buffer VGPRs are structurally mandatory; RA cannot collapse them);
//  - waits are literal s_waitcnt vmcnt(N), counted, never 0 in steady
//    state (AITER/HipKittens pattern);
//  - sched_barrier(0) immediately after each wait stops MFMA hoisting
//    above it (the guide's rule-#18 VERIFIED fence usage).
// vmcnt ledger: prologue 3 chunks = 24 outstanding; each phase issues 8
// more (<=32) then vmcnt(24) retires exactly the ring it consumes (FIFO
// in-order retirement). Epilogue drains 24->16->8->0.
// Verification signal: VGPR_Count must be >=200 (else compile-level fail).
//
// Outputs: Cf (fp32,+res row-major) | Cb (bf16 row-major) | Csw (bf16
// swizzled for the next GEMM, K_consumer = N) ; cols >= ctcol0 (Ct!=null)
// go transposed to Ct (attention V^T). M,N multiples of 64, kt=K/32
// a multiple of 4 and >= 8 (kt = 32 or 64 here).
// ---------------------------------------------------------------------------
#define GLOAD(dst, p)                                                       \
    asm volatile("global_load_dwordx4 %0, %1, off"                          \
                 : "=v"(dst) : "v"(p))

#define WAITV(n) asm volatile("s_waitcnt vmcnt(" #n ")")

#define SBAR() __builtin_amdgcn_sched_barrier(0)

#define PHASE_LOAD(R, C) do {                                               \
    const long long o_ = (long long)(C) << 9;                               \
    GLOAD(Ab[R][0], pa[0] + o_); GLOAD(Ab[R][1], pa[1] + o_);               \
    GLOAD(Ab[R][2], pa[2] + o_); GLOAD(Ab[R][3], pa[3] + o_);               \
    GLOAD(Bb[R][0], pb[0] + o_); GLOAD(Bb[R][1], pb[1] + o_);               \
    GLOAD(Bb[R][2], pb[2] + o_); GLOAD(Bb[R][3], pb[3] + o_);               \
} while (0)

#define MFMA_CHUNK(R) do {                                                  \
    _Pragma("unroll")                                                       \
    for (int i_ = 0; i_ < 4; i_++)                                          \
    _Pragma("unroll")                                                       \
    for (int j_ = 0; j_ < 4; j_++)                                          \
        acc[i_][j_] = __builtin_amdgcn_mfma_f32_16x16x32_bf16(              \
            Ab[R][i_], Bb[R][j_], acc[i_][j_], 0, 0, 0);                    \
} while (0)

__global__ __launch_bounds__(64, 2) void gemm_sw_k(
    const unsigned short* __restrict__ Asw,
    const unsigned short* __restrict__ Bsw,
    const float* __restrict__ bias,
    const float* __restrict__ res,
    float* __restrict__ Cf,
    unsigned short* __restrict__ Cb,
    unsigned short* __restrict__ Csw,
    unsigned short* __restrict__ Ct, int ctcol0,
    int M, int N, int K, int ldC, int relu)
{
    const int l = threadIdx.x;

    int bx = blockIdx.x, by = blockIdx.y;
    {
        int nbx = gridDim.x;
        int nb  = nbx * gridDim.y;
        if ((nb & 7) == 0) {
            int bid = by * nbx + bx;
            int nid = (bid & 7) * (nb >> 3) + (bid >> 3);
            by = nid / nbx;
            bx = nid - by * nbx;
        }
    }
    const int m0 = by * 64;
    const int n0 = bx * 64;
    const int r16 = l & 15;
    const int qb  = l >> 4;
    const int kt = K >> 5;

    // fragment base pointers: contiguous 16B per lane
    const unsigned short* pa[4];
#pragma unroll
    for (int i = 0; i < 4; i++)
        pa[i] = Asw + ((long long)(((m0 >> 4) + i) * kt) << 9) + l * 8;
    const unsigned short* pb[4];
#pragma unroll
    for (int j = 0; j < 4; j++)
        pb[j] = Bsw + ((long long)(((n0 >> 4) + j) * kt) << 9) + l * 8;

    v4f acc[4][4];
#pragma unroll
    for (int i = 0; i < 4; i++)
#pragma unroll
        for (int j = 0; j < 4; j++) acc[i][j] = (v4f){0.f, 0.f, 0.f, 0.f};

    v8bf Ab[4][4], Bb[4][4];

    // prologue: chunks 0,1,2 -> rings 0,1,2 (24 loads outstanding)
    PHASE_LOAD(0, 0);
    PHASE_LOAD(1, 1);
    PHASE_LOAD(2, 2);

    // steady state: issue 8 loads (<=32 out), wait vmcnt(24) (retires the
    // ring about to be consumed), fence, 16 MFMAs. Loads issued 3 phases
    // ahead of their consumers; wait count is literal and constant.
    int s = 0;
    for (; s < kt - 4; s += 4) {
        PHASE_LOAD(3, s + 3); WAITV(24); SBAR(); MFMA_CHUNK(0);
        PHASE_LOAD(0, s + 4); WAITV(24); SBAR(); MFMA_CHUNK(1);
        PHASE_LOAD(1, s + 5); WAITV(24); SBAR(); MFMA_CHUNK(2);
        PHASE_LOAD(2, s + 6); WAITV(24); SBAR(); MFMA_CHUNK(3);
    }
    // epilogue: s == kt-4; rings 0,1,2 hold kt-4,kt-3,kt-2 (24 out).
    PHASE_LOAD(3, kt - 1); WAITV(24); SBAR(); MFMA_CHUNK(0);
    WAITV(16); SBAR(); MFMA_CHUNK(1);
    WAITV(8);  SBAR(); MFMA_CHUNK(2);
    WAITV(0);  SBAR(); MFMA_CHUNK(3);

    float bv[4];
#pragma unroll
    for (int j = 0; j < 4; j++) bv[j] = bias[n0 + 16 * j + r16];
    const int colbase = n0 + r16;
    const int nt = N >> 5;
#pragma unroll
    for (int i = 0; i < 4; i++) {
        int rowb = m0 + 16 * i + qb * 4;
#pragma unroll
        for (int j = 0; j < 4; j++) {
            int col = colbase + 16 * j;
            float v[4];
#pragma unroll
            for (int r = 0; r < 4; r++) v[r] = acc[i][j][r] + bv[j];
            if (Ct && col >= ctcol0) {
                ushort4 o;
                o.x = f2bfu(v[0]); o.y = f2bfu(v[1]);
                o.z = f2bfu(v[2]); o.w = f2bfu(v[3]);
                *(ushort4*)(Ct + ((long long)(rowb >> 10) << 20)
                            + (long long)(col - ctcol0) * 1024 + (rowb & 1023)) = o;
            } else if (Csw) {
#pragma unroll
                for (int r = 0; r < 4; r++) {
                    int row = rowb + r;
                    float vv = v[r];
                    if (relu) vv = fmaxf(vv, 0.f);
                    Csw[swidx(row, col, nt)] = f2bfu(vv);
                }
            } else {
#pragma unroll
                for (int r = 0; r < 4; r++) {
                    int row = rowb + r;
                    long long off = (long long)row * ldC + col;
                    float vv = v[r];
                    if (res)  vv += res[off];
                    if (relu) vv = fmaxf(vv, 0.f);
                    if (Cf) Cf[off] = vv;
                    if (Cb) ((unsigned short*)Cb)[off] = f2bfu(vv);
                }
            }
        }
    }
}

// ---------------------------------------------------------------------------
// LDS-staged GEMM (R5) — kept for the conv frontend (row-remapped A).
// ---------------------------------------------------------------------------
__global__ __launch_bounds__(256) void gemm_mfma_k(
    const __hip_bfloat16* __restrict__ A, int rpbA, long long bstrideA, int ldA,
    const __hip_bfloat16* __restrict__ B,
    const float* __restrict__ bias,
    const float* __restrict__ res,
    float* __restrict__ Cf,
    __hip_bfloat16* __restrict__ Cb,
    int M, int N, int K, int ldC, int relu)
{
    __shared__ __align__(16) __hip_bfloat16 As[2][8][64][8];
    __shared__ __align__(16) __hip_bfloat16 Bs[2][4][64][8];
    const int t  = threadIdx.x;
    const int w  = t >> 6;
    const int l  = t & 63;
    const int m0 = blockIdx.y * 128;
    const int n0 = blockIdx.x * 64;
    const int r16 = l & 15;
    const int qb  = l >> 4;
    const int wm = w >> 1, wn = w & 1;

    const __hip_bfloat16* gA[2];
#pragma unroll
    for (int tt = 0; tt < 2; tt++) {
        int arow = m0 + 16 * (2 * w + tt) + r16;
        gA[tt] = A + (long long)(arow / rpbA) * bstrideA
                   + (long long)(arow % rpbA) * ldA + qb * 8;
    }
    const __hip_bfloat16* gB = B + (long long)(n0 + 16 * w + r16) * K + qb * 8;

    v4f acc[4][2];
#pragma unroll
    for (int i = 0; i < 4; i++)
#pragma unroll
        for (int j = 0; j < 2; j++) acc[i][j] = (v4f){0.f, 0.f, 0.f, 0.f};

    GLDS16(gA[0], &As[0][2 * w + 0][0][0]);
    GLDS16(gA[1], &As[0][2 * w + 1][0][0]);
    GLDS16(gB,    &Bs[0][w][0][0]);
    __syncthreads();

    int cur = 0;
    for (int k0 = 32; k0 < K; k0 += 32) {
        v8bf af[4], bfr[2];
#pragma unroll
        for (int i = 0; i < 4; i++) af[i]  = *(const v8bf*)(&As[cur][4 * wm + i][l][0]);
#pragma unroll
        for (int j = 0; j < 2; j++) bfr[j] = *(const v8bf*)(&Bs[cur][2 * wn + j][l][0]);
        GLDS16(gA[0] + k0, &As[cur ^ 1][2 * w + 0][0][0]);
        GLDS16(gA[1] + k0, &As[cur ^ 1][2 * w + 1][0][0]);
        GLDS16(gB + k0,    &Bs[cur ^ 1][w][0][0]);
#pragma unroll
        for (int i = 0; i < 4; i++)
#pragma unroll
            for (int j = 0; j < 2; j++)
                acc[i][j] = __builtin_amdgcn_mfma_f32_16x16x32_bf16(
                    af[i], bfr[j], acc[i][j], 0, 0, 0);
        __syncthreads();
        cur ^= 1;
    }
    {
        v8bf af[4], bfr[2];
#pragma unroll
        for (int i = 0; i < 4; i++) af[i]  = *(const v8bf*)(&As[cur][4 * wm + i][l][0]);
#pragma unroll
        for (int j = 0; j < 2; j++) bfr[j] = *(const v8bf*)(&Bs[cur][2 * wn + j][l][0]);
#pragma unroll
        for (int i = 0; i < 4; i++)
#pragma unroll
            for (int j = 0; j < 2; j++)
                acc[i][j] = __builtin_amdgcn_mfma_f32_16x16x32_bf16(
                    af[i], bfr[j], acc[i][j], 0, 0, 0);
    }

    float bv[2];
#pragma unroll
    for (int j = 0; j < 2; j++) bv[j] = bias[n0 + 32 * wn + 16 * j + r16];
    const int colbase = n0 + 32 * wn + r16;
#pragma unroll
    for (int i = 0; i < 4; i++) {
        int rowb = m0 + 64 * wm + 16 * i + qb * 4;
#pragma unroll
        for (int j = 0; j < 2; j++) {
            int col = colbase + 16 * j;
#pragma unroll
            for (int r = 0; r < 4; r++) {
                int row = rowb + r;
                if (row >= M) continue;
                long long off = (long long)row * ldC + col;
                float vv = acc[i][j][r] + bv[j];
                if (res)  vv += res[off];
                if (relu) vv = fmaxf(vv, 0.f);
                if (Cf) Cf[off] = vv;
                if (Cb) ((unsigned short*)Cb)[off] = f2bfu(vv);
            }
        }
    }
}

// ---------------------------------------------------------------------------
// MFMA softsign attention. Output written in SWIZZLED layout (K=1024 -> 32).
// ---------------------------------------------------------------------------
__global__ __launch_bounds__(256) void attn_mfma_k(
    const unsigned short* __restrict__ QKV,
    const unsigned short* __restrict__ Vt,
    unsigned short* __restrict__ Osw)
{
    __shared__ __align__(16) unsigned short lds[25600];
    const int t = threadIdx.x, w = t >> 6, l = t & 63;
    const int bh = blockIdx.y, b = bh >> 4, h = bh & 15;
    const int s0 = blockIdx.x << 7;
    const int r16 = l & 15, q4 = l >> 4;
    const long long qrow0 = (long long)(b << 10) + s0;
    const int hoff = h << 6;

#pragma unroll
    for (int mi = 0; mi < 2; mi++)
#pragma unroll
        for (int kk = 0; kk < 2; kk++) {
            const unsigned short* g = QKV + (qrow0 + 32 * w + 16 * mi + r16) * 3072
                                      + hoff + 32 * kk + q4 * 8;
            GLDS16(g, &lds[(w * 4 + mi * 2 + kk) * 512]);
        }
    __syncthreads();
    v8bf qf[2][2];
#pragma unroll
    for (int mi = 0; mi < 2; mi++)
#pragma unroll
        for (int kk = 0; kk < 2; kk++)
            qf[mi][kk] = *(const v8bf*)&lds[(w * 4 + mi * 2 + kk) * 512 + l * 8];

    v4f oacc[2][4];
#pragma unroll
    for (int i = 0; i < 2; i++)
#pragma unroll
        for (int j = 0; j < 4; j++) oacc[i][j] = (v4f){0.f, 0.f, 0.f, 0.f};

    for (int t0 = 0; t0 < 1024; t0 += 64) {
#pragma unroll
        for (int rr = 0; rr < 2; rr++) {
            int r = 2 * w + rr, kk = r >> 2, j = r & 3;
            const unsigned short* gk = QKV
                + ((long long)(b << 10) + t0 + 16 * j + r16) * 3072
                + 1024 + hoff + 32 * kk + q4 * 8;
            GLDS16(gk, &lds[8192 + r * 512]);
            const unsigned short* gv = Vt + ((long long)b << 20)
                + (long long)(hoff + 16 * j + r16) * 1024 + t0 + 32 * kk + q4 * 8;
            GLDS16(gv, &lds[12288 + r * 512]);
        }
        __syncthreads();

        v8bf kf[2][4];
#pragma unroll
        for (int kk = 0; kk < 2; kk++)
#pragma unroll
            for (int j = 0; j < 4; j++)
                kf[kk][j] = *(const v8bf*)&lds[8192 + (kk * 4 + j) * 512 + l * 8];
        v4f sc[2][4];
#pragma unroll
        for (int i = 0; i < 2; i++)
#pragma unroll
            for (int j = 0; j < 4; j++) sc[i][j] = (v4f){0.f, 0.f, 0.f, 0.f};
#pragma unroll
        for (int kk = 0; kk < 2; kk++)
#pragma unroll
            for (int mi = 0; mi < 2; mi++)
#pragma unroll
                for (int j = 0; j < 4; j++)
                    sc[mi][j] = __builtin_amdgcn_mfma_f32_16x16x32_bf16(
                        qf[mi][kk], kf[kk][j], sc[mi][j], 0, 0, 0);

#pragma unroll
        for (int mi = 0; mi < 2; mi++)
#pragma unroll
            for (int j = 0; j < 4; j++)
#pragma unroll
                for (int r = 0; r < 4; r++) {
                    float v = sc[mi][j][r] * 0.125f;
                    float p = v * __builtin_amdgcn_rcpf(1.0f + fabsf(v));
                    lds[16384 + (32 * w + 16 * mi + q4 * 4 + r) * 72 + 16 * j + r16] = f2bfu(p);
                }

        v8bf pf[2][2], vf[2][4];
#pragma unroll
        for (int mi = 0; mi < 2; mi++)
#pragma unroll
            for (int kk = 0; kk < 2; kk++)
                pf[mi][kk] = *(const v8bf*)&lds[16384 + (32 * w + 16 * mi + r16) * 72
                                                + 32 * kk + q4 * 8];
#pragma unroll
        for (int kk = 0; kk < 2; kk++)
#pragma unroll
            for (int j = 0; j < 4; j++)
                vf[kk][j] = *(const v8bf*)&lds[12288 + (kk * 4 + j) * 512 + l * 8];
#pragma unroll
        for (int kk = 0; kk < 2; kk++)
#pragma unroll
            for (int mi = 0; mi < 2; mi++)
#pragma unroll
                for (int j = 0; j < 4; j++)
                    oacc[mi][j] = __builtin_amdgcn_mfma_f32_16x16x32_bf16(
                        pf[mi][kk], vf[kk][j], oacc[mi][j], 0, 0, 0);
        __syncthreads();
    }

#pragma unroll
    for (int mi = 0; mi < 2; mi++)
#pragma unroll
        for (int j = 0; j < 4; j++)
#pragma unroll
            for (int r = 0; r < 4; r++)
                lds[(32 * w + 16 * mi + q4 * 4 + r) * 72 + 16 * j + r16] =
                    f2bfu(oacc[mi][j][r]);
    __syncthreads();
    {
        int row = t >> 1, ch = (t & 1) << 5;
        int grow = (int)qrow0 + row;
#pragma unroll
        for (int i = 0; i < 4; i++) {
            int c0 = hoff + ch + 8 * i;
            v8us vv = *(const v8us*)&lds[row * 72 + ch + 8 * i];
            *(v8us*)(Osw + swidx(grow, c0, 32)) = vv;
        }
    }
}

// ---------------------------------------------------------------------------
// LayerNorm (torch-style), output bf16 in SWIZZLED layout (K=1024).
// ---------------------------------------------------------------------------
__global__ __launch_bounds__(256) void layernorm_k(
    const float* __restrict__ x, const float* __restrict__ w,
    const float* __restrict__ b, unsigned short* __restrict__ ysw)
{
    int row = blockIdx.x;
    int t = threadIdx.x;
    float4 v = ((const float4*)(x + ((long long)row << 10)))[t];
    float s = v.x + v.y + v.z + v.w;
#pragma unroll
    for (int o = 32; o; o >>= 1) s += __shfl_down(s, o);
    __shared__ float red[4];
    __shared__ float red2[4];
    int wid = t >> 6, lane = t & 63;
    if (lane == 0) red[wid] = s;
    __syncthreads();
    float mean = (red[0] + red[1] + red[2] + red[3]) * (1.0f / 1024.0f);
    float dx = v.x - mean, dy = v.y - mean, dz = v.z - mean, dw = v.w - mean;
    float sq = dx * dx + dy * dy + dz * dz + dw * dw;
#pragma unroll
    for (int o = 32; o; o >>= 1) sq += __shfl_down(sq, o);
    if (lane == 0) red2[wid] = sq;
    __syncthreads();
    float var = (red2[0] + red2[1] + red2[2] + red2[3]) * (1.0f / 1023.0f);
    float inv = 1.0f / (sqrtf(var) + 1e-6f);
    float4 W  = ((const float4*)w)[t];
    float4 Bv = ((const float4*)b)[t];
    ushort4 o;
    o.x = f2bfu(W.x * (dx * inv) + Bv.x);
    o.y = f2bfu(W.y * (dy * inv) + Bv.y);
    o.z = f2bfu(W.z * (dz * inv) + Bv.z);
    o.w = f2bfu(W.w * (dw * inv) + Bv.w);
    int c0 = t << 2;
    *(ushort4*)(ysw + swidx(row, c0, 32)) = o;
}

// ---------------------------------------------------------------------------
__global__ __launch_bounds__(256) void add_pos_k(float* __restrict__ h)
{
    int idx = blockIdx.x * 256 + threadIdx.x;
    int d = idx & 1023;
    int s = (idx >> 10) & 1023;
    int e = d & ~1;
    float div = expf(-9.210340371976184f * (float)e * (1.0f / 1024.0f));
    float arg = (float)s * div;
    float pe = (d & 1) ? cosf(arg) : sinf(arg);
    h[idx] += pe;
}

__global__ __launch_bounds__(256) void convert_k(
    const float* __restrict__ src, unsigned short* __restrict__ dst, int n4)
{
    int i = blockIdx.x * 256 + threadIdx.x;
    if (i >= n4) return;
    float4 v = ((const float4*)src)[i];
    ushort4 o;
    o.x = f2bfu(v.x); o.y = f2bfu(v.y); o.z = f2bfu(v.z); o.w = f2bfu(v.w);
    ((ushort4*)dst)[i] = o;
}

// Layer weights fp32 row-major -> bf16 SWIZZLED, all 6 matrices, one launch.
// dst layout (us): q,k,v,o (1M each), f1 (2M), f2 (2M) — contiguous.
__global__ __launch_bounds__(256) void convert_layer_sw_k(
    const float* __restrict__ q, const float* __restrict__ k,
    const float* __restrict__ v, const float* __restrict__ o,
    const float* __restrict__ f1, const float* __restrict__ f2,
    unsigned short* __restrict__ dst)
{
    int idx = blockIdx.x * 256 + threadIdx.x;   // float4 index, [0, 2M)
    const float* src;
    unsigned short* db;
    int Ksh, rf;
    if (idx < 0x100000) {
        int region = idx >> 18;
        rf = idx & 0x3FFFF;
        src = (region == 0) ? q : (region == 1) ? k : (region == 2) ? v : o;
        db = dst + ((long long)region << 20);
        Ksh = 10;
    } else if (idx < 0x180000) {
        rf = idx - 0x100000; src = f1; db = dst + (4LL << 20); Ksh = 10;
    } else {
        rf = idx - 0x180000; src = f2; db = dst + (6LL << 20); Ksh = 11;
    }
    float4 vv = ((const float4*)src)[rf];
    int flatf = rf << 2;
    int n  = flatf >> Ksh;
    int k0 = flatf & ((1 << Ksh) - 1);
    ushort4 ov;
    ov.x = f2bfu(vv.x); ov.y = f2bfu(vv.y); ov.z = f2bfu(vv.z); ov.w = f2bfu(vv.w);
    *(ushort4*)(db + swidx(n, k0, 1 << (Ksh - 5))) = ov;
}

__global__ __launch_bounds__(256) void concat3_k(
    const float* __restrict__ a, const float* __restrict__ b,
    const float* __restrict__ c, float* __restrict__ o)
{
    int i = blockIdx.x * 256 + threadIdx.x;
    o[i] = (i < 1024) ? a[i] : ((i < 2048) ? b[i - 1024] : c[i - 2048]);
}

__global__ __launch_bounds__(256) void reorder_w_k(
    const float* __restrict__ src, unsigned short* __restrict__ dst, int OC, int IC)
{
    int idx = blockIdx.x * 256 + threadIdx.x;
    if (idx >= OC * IC * 3) return;
    int k  = idx % 3;
    int ic = (idx / 3) % IC;
    int oc = idx / (3 * IC);
    dst[(oc * 3 + k) * IC + ic] = f2bfu(src[idx]);
}

// meanpool split: 256-block partial pass (16 rows each, all 1024 d) then a
// 16-block reduce. Old single-pass version ran on only 16 CUs pulling 16 MB.
__global__ __launch_bounds__(256) void meanpool_part_k(
    const float* __restrict__ h, float* __restrict__ part)
{
    int g = blockIdx.x;                 // g = b*64 + rblk
    int b = g >> 6, rblk = g & 63;
    const float4* base = (const float4*)(h + ((long long)b << 20)
                                           + ((long long)(rblk * 16) << 10));
    float4 s = {0.f, 0.f, 0.f, 0.f};
#pragma unroll
    for (int i = 0; i < 16; i++) {
        float4 v = base[i * 256 + threadIdx.x];
        s.x += v.x; s.y += v.y; s.z += v.z; s.w += v.w;
    }
    ((float4*)part)[g * 256 + threadIdx.x] = s;
}

__global__ __launch_bounds__(256) void meanpool_red_k(
    const float* __restrict__ part, float* __restrict__ pooled)
{
    int idx = blockIdx.x * 256 + threadIdx.x;   // 4096: b = idx>>10, d = idx&1023
    int b = idx >> 10, d = idx & 1023;
    const float* p = part + ((long long)(b * 64) << 10) + d;
    float s = 0.f;
#pragma unroll 8
    for (int r = 0; r < 64; r++) s += p[r << 10];
    pooled[idx] = s * (1.0f / 1024.0f);
}

__global__ __launch_bounds__(256) void fc_k(
    const float* __restrict__ p, const float* __restrict__ w,
    const float* __restrict__ fb, float* __restrict__ out)
{
    int b = blockIdx.x, t = threadIdx.x;
    float s = 0.f;
    for (int i = t; i < 1024; i += 256) s += p[(b << 10) + i] * w[i];
#pragma unroll
    for (int o = 32; o; o >>= 1) s += __shfl_down(s, o);
    __shared__ float red[4];
    if ((t & 63) == 0) red[t >> 6] = s;
    __syncthreads();
    if (t == 0) out[b] = red[0] + red[1] + red[2] + red[3] + fb[0];
}

// ---------------------------------------------------------------------------
extern "C" void kernel_launch(void* const* d_in, const int* in_sizes, int n_in,
                              void* d_out, int out_size, void* d_ws, size_t ws_size,
                              hipStream_t stream)
{
    const float* x    = (const float*)d_in[0];
    const float* c1w  = (const float*)d_in[1];
    const float* c1b  = (const float*)d_in[2];
    const float* c2w  = (const float*)d_in[3];
    const float* c2b  = (const float*)d_in[4];
    const float* lnAw = (const float*)d_in[5];
    const float* lnAb = (const float*)d_in[6];
    const float* qw   = (const float*)d_in[7];
    const float* qbi  = (const float*)d_in[8];
    const float* kw   = (const float*)d_in[9];
    const float* kbi  = (const float*)d_in[10];
    const float* vw   = (const float*)d_in[11];
    const float* vbi  = (const float*)d_in[12];
    const float* ow   = (const float*)d_in[13];
    const float* obi  = (const float*)d_in[14];
    const float* lnBw = (const float*)d_in[15];
    const float* lnBb = (const float*)d_in[16];
    const float* f1w  = (const float*)d_in[17];
    const float* f1b  = (const float*)d_in[18];
    const float* f2w  = (const float*)d_in[19];
    const float* f2b  = (const float*)d_in[20];
    const float* fcw  = (const float*)d_in[21];
    const float* fcb  = (const float*)d_in[22];
    float* out = (float*)d_out;

    float* ws = (float*)d_ws;
    typedef __hip_bfloat16 bf;
    typedef unsigned short us;
    float* h    = ws;                          // 4,194,304 f
    us* hn_b    = (us*)(ws + 4194304);         // 4M us (swizzled activations)
    us* qkv_b   = (us*)(ws + 6291456);         // [4096][3072] us row-major
    us* ff_b    = qkv_b;                       // [4096][2048] swizzled overlay
    us* wq_b    = (us*)(ws + 12582912);        // swizzled: q,k,v,o,f1,f2
    us* wo_b    = (us*)(ws + 14155776);
    us* wf1_b   = (us*)(ws + 14680064);
    us* wf2_b   = (us*)(ws + 15728640);
    us* xb      = (us*)(ws + 16777216);
    us* h1b     = (us*)(ws + 16912896);
    us* w1t_b   = (us*)(ws + 17963520);
    us* w2t_b   = (us*)(ws + 18012672);
    float* pooled = ws + 18799104;             // 4,096 f
    us* Vt      = (us*)(ws + 18803200);        // [4][1024 d][1024 t] us
    float* bqkv = ws + 20900352;               // 3,072 f
    float* mp_part = ws + 20903424;            // 262,144 f (meanpool partials)

    convert_k<<<dim3(257), 256, 0, stream>>>(x, xb, 65792);
    reorder_w_k<<<dim3(384),  256, 0, stream>>>(c1w, w1t_b, 512, 64);
    reorder_w_k<<<dim3(6144), 256, 0, stream>>>(c2w, w2t_b, 1024, 512);

    // conv1: M=4104, N=512, K=192 (LDS-staged kernel, row-remapped A)
    gemm_mfma_k<<<dim3(8, 33), 256, 0, stream>>>(
        (const bf*)xb, 1026, 1028LL * 64, 64, (const bf*)w1t_b,
        c1b, nullptr, nullptr, (bf*)h1b, 4104, 512, 192, 512, 0);
    // conv2: M=4096, N=1024, K=1536
    gemm_mfma_k<<<dim3(16, 32), 256, 0, stream>>>(
        (const bf*)h1b, 1024, 1026LL * 512, 512, (const bf*)w2t_b,
        c2b, nullptr, h, nullptr, 4096, 1024, 1536, 1024, 0);
    add_pos_k<<<dim3(16384), 256, 0, stream>>>(h);

    for (int l = 0; l < 4; l++) {
        long long wo  = (long long)l * 1048576;
        long long wo2 = (long long)l * 2097152;
        convert_layer_sw_k<<<dim3(8192), 256, 0, stream>>>(
            qw + wo, kw + wo, vw + wo, ow + wo, f1w + wo2, f2w + wo2, wq_b);
        concat3_k<<<dim3(12), 256, 0, stream>>>(qbi + l * 1024, kbi + l * 1024,
                                                vbi + l * 1024, bqkv);

        layernorm_k<<<dim3(4096), 256, 0, stream>>>(h, lnAw + l * 1024, lnAb + l * 1024, hn_b);
        // fused QKV: N=3072; Q,K swizzled to qkv_b; V transposed to Vt
        gemm_sw_k<<<dim3(48, 64), 64, 0, stream>>>(
            hn_b, wq_b, bqkv, nullptr, nullptr, qkv_b, nullptr, Vt, 2048,
            4096, 3072, 1024, 3072, 0);
        attn_mfma_k<<<dim3(8, 64), 256, 0, stream>>>(qkv_b, Vt, hn_b);
        // O-proj: out fp32 h += res
        gemm_sw_k<<<dim3(16, 64), 64, 0, stream>>>(
            hn_b, wo_b, obi + l * 1024, h, h, nullptr, nullptr, nullptr, 0,
            4096, 1024, 1024, 1024, 0);
        layernorm_k<<<dim3(4096), 256, 0, stream>>>(h, lnBw + l * 1024, lnBb + l * 1024, hn_b);
        // FF1: out swizzled bf16 (+relu)
        gemm_sw_k<<<dim3(32, 64), 64, 0, stream>>>(
            hn_b, wf1_b, f1b + l * 2048, nullptr, nullptr, nullptr, ff_b, nullptr, 0,
            4096, 2048, 1024, 2048, 1);
        // FF2: out fp32 h += res
        gemm_sw_k<<<dim3(16, 64), 64, 0, stream>>>(
            ff_b, wf2_b, f2b + l * 1024, h, h, nullptr, nullptr, nullptr, 0,
            4096, 1024, 2048, 1024, 0);
    }

    meanpool_part_k<<<dim3(256), 256, 0, stream>>>(h, mp_part);
    meanpool_red_k<<<dim3(16), 256, 0, stream>>>(mp_part, pooled);
    fc_k<<<dim3(4), 256, 0, stream>>>(pooled, fcw, fcb, out);
}